// Round 14
// baseline (945.165 us; speedup 1.0000x reference)
//
#include <hip/hip_runtime.h>
#include <cstddef>

#define T_     8000
#define L_     803
#define C_     256
#define D_     512
#define NB_    32
#define FK_    20
#define NBATCH 4
#define EPS_   1e-5f

#define NBLK   52            // 13 l-tiles x 4 batch; one block owns full C/D of a strip
#define NTHR   1024          // 16 waves -> 4 waves/SIMD
#define NTH_G  (NBLK * NTHR)
#define SG     1040          // LDS k-group stride bytes: 64 cols * 16B + 16B pad

typedef __attribute__((ext_vector_type(8))) short bf16x8;
typedef __attribute__((ext_vector_type(4))) short shortx4;
typedef __attribute__((ext_vector_type(4))) float f32x4;

__device__ __forceinline__ short f2bf(float x) {
  unsigned u = __float_as_uint(x);
  u += 0x7FFF + ((u >> 16) & 1);   // RNE
  return (short)(u >> 16);
}
__device__ __forceinline__ float bf2f(short u) {
  return __uint_as_float(((unsigned)(unsigned short)u) << 16);
}

struct __align__(64) Bar { unsigned cnt; unsigned phase; unsigned pad[14]; };

__device__ __forceinline__ void bar_heavy(Bar* b, unsigned nblk, int tid) {
  __syncthreads();
  if (tid == 0) {
    __threadfence();
    unsigned ph = __hip_atomic_load(&b->phase, __ATOMIC_RELAXED, __HIP_MEMORY_SCOPE_AGENT);
    unsigned prev = __hip_atomic_fetch_add(&b->cnt, 1u, __ATOMIC_RELAXED, __HIP_MEMORY_SCOPE_AGENT);
    if (prev == nblk - 1) {
      __hip_atomic_store(&b->cnt, 0u, __ATOMIC_RELAXED, __HIP_MEMORY_SCOPE_AGENT);
      __hip_atomic_store(&b->phase, ph + 1u, __ATOMIC_RELEASE, __HIP_MEMORY_SCOPE_AGENT);
    } else {
      while (__hip_atomic_load(&b->phase, __ATOMIC_RELAXED, __HIP_MEMORY_SCOPE_AGENT) == ph)
        __builtin_amdgcn_s_sleep(2);
    }
    __threadfence();
  }
  __syncthreads();
}

struct KParams {
  const float *x, *w_enc, *w1, *wd, *w2, *w_dec;
  const float *g1, *bb1, *m1, *v1;
  const float *g2, *bb2, *m2, *v2;
  const float *g3, *bb3, *m3, *v3;
  float *out;
  float *s1, *o1, *s2, *o2, *s3, *o3;
  float *yb;                  // y [n][l][c] f32
  short *w1b, *w2b;           // bf16 weights
  unsigned short *zg;         // z publish: [layer][logical blk][64][512] bf16
  unsigned *ct;               // per-block monotone layer counter [52]
  Bar *gbar;
};

// ---------- full-grid prep: BN fold + weight bf16 conversion ----------
__global__ __launch_bounds__(256) void prep_kernel(KParams p) {
  const int gtid = blockIdx.x * 256 + threadIdx.x;
  const int stride = gridDim.x * 256;
  for (int i = gtid; i < NB_ * C_; i += stride) {
    float s = p.g1[i] * rsqrtf(p.v1[i] + EPS_);
    p.s1[i] = s; p.o1[i] = p.bb1[i] - p.m1[i] * s;
  }
  for (int i = gtid; i < NB_ * D_; i += stride) {
    float s2 = p.g2[i] * rsqrtf(p.v2[i] + EPS_);
    p.s2[i] = s2; p.o2[i] = p.bb2[i] - p.m2[i] * s2;
    float s3 = p.g3[i] * rsqrtf(p.v3[i] + EPS_);
    p.s3[i] = s3; p.o3[i] = p.bb3[i] - p.m3[i] * s3;
  }
  for (int i = gtid; i < NB_ * D_ * C_ / 4; i += stride) {
    float4 a = ((const float4*)p.w1)[i];
    float4 b = ((const float4*)p.w2)[i];
    shortx4 sa, sb;
    sa[0] = f2bf(a.x); sa[1] = f2bf(a.y); sa[2] = f2bf(a.z); sa[3] = f2bf(a.w);
    sb[0] = f2bf(b.x); sb[1] = f2bf(b.y); sb[2] = f2bf(b.z); sb[3] = f2bf(b.w);
    *(shortx4*)&p.w1b[4 * i] = sa;
    *(shortx4*)&p.w2b[4 * i] = sb;
  }
}

__global__ __launch_bounds__(NTHR) void tasnet_fused(KParams p) {
  const int tid = threadIdx.x;
  const int bid = blockIdx.x;
  const int gtid = bid * NTHR + tid;

  // XCD-aware strip placement (bid%8 -> XCD heuristic); kept from r12.
  const int xcd = bid & 7, slot = bid >> 3;
  const int n = xcd & 3;
  const int xt = (xcd < 4) ? slot : 7 + slot;
  const int lg = n * 13 + xt;           // logical block id (zg/ct indexing)
  const int l0 = xt * 64;

  const int lane = tid & 63, wv = tid >> 6;   // wv 0..15
  const int frow = lane & 15, kg = lane >> 4;

  __shared__ __align__(16) char BsRaw[64 * SG];   // 66560 B
  __shared__ __align__(16) char ZsRaw[64 * SG];   // z tile [dgrp][col][8] bf16

  // ---------------- encoder -> registers ----------------
  // element (jb,jj): c = wv*16 + kg*4 + jj ; l = l0 + jb*16 + frow
  f32x4 hreg[4], xer[4];
  {
    const float* xn = p.x + (size_t)n * T_;
    const int cb = wv * 16 + kg * 4;
#pragma unroll
    for (int jb = 0; jb < 4; ++jb) {
      int gl = l0 + jb * 16 + frow;
      int t0 = gl * 10 - 20;
      float xw[FK_];
#pragma unroll
      for (int k = 0; k < FK_; ++k) {
        int t = t0 + k;
        xw[k] = (t >= 0 && t < T_) ? xn[t] : 0.f;
      }
#pragma unroll
      for (int jj = 0; jj < 4; ++jj) {
        const float* w = p.w_enc + (cb + jj) * FK_;
        float acc = 0.f;
#pragma unroll
        for (int k = 0; k < FK_; ++k) acc = fmaf(xw[k], w[k], acc);
        hreg[jb][jj] = acc;
        xer[jb][jj] = acc;
      }
    }
  }

  // ---------------- 32 residual blocks, fully fused ----------------
  for (int layer = 0; layer < NB_; ++layer) {
    const int dil = 1 << (layer & 7);
    const float* s1p = p.s1 + layer * C_;
    const float* o1p = p.o1 + layer * C_;
    const float* s2p = p.s2 + layer * D_;
    const float* o2p = p.o2 + layer * D_;
    const float* s3p = p.s3 + layer * D_;
    const float* o3p = p.o3 + layer * D_;

    // ===== B1 = BN1(hreg) -> Bs =====
    {
      const int cb = wv * 16 + kg * 4;
      float4 s1v = *(const float4*)(s1p + cb);
      float4 o1v = *(const float4*)(o1p + cb);
#pragma unroll
      for (int jb = 0; jb < 4; ++jb) {
        shortx4 pk;
        pk[0] = f2bf(fmaf(hreg[jb][0], s1v.x, o1v.x));
        pk[1] = f2bf(fmaf(hreg[jb][1], s1v.y, o1v.y));
        pk[2] = f2bf(fmaf(hreg[jb][2], s1v.z, o1v.z));
        pk[3] = f2bf(fmaf(hreg[jb][3], s1v.w, o1v.w));
        *(shortx4*)(BsRaw + (cb >> 3) * SG + (jb * 16 + frow) * 16 + (kg & 1) * 8) = pk;
      }
    }
    __syncthreads();

    // ===== stage1 MFMA: acc1[d 512][l 64] ; wave owns 32 d rows =====
    f32x4 acc1[2][4] = {};
    {
      const short* W1 = p.w1b + (size_t)layer * D_ * C_;
#pragma unroll
      for (int k0 = 0; k0 < 8; ++k0) {
        int kb = k0 * 32 + kg * 8;
        bf16x8 bfr[4];
#pragma unroll
        for (int jb = 0; jb < 4; ++jb)
          bfr[jb] = *(bf16x8*)(BsRaw + (k0 * 4 + kg) * SG + (jb * 16 + frow) * 16);
#pragma unroll
        for (int ia = 0; ia < 2; ++ia) {
          bf16x8 af = *(const bf16x8*)(W1 + (size_t)(wv * 32 + ia * 16 + frow) * C_ + kb);
#pragma unroll
          for (int jb = 0; jb < 4; ++jb)
            acc1[ia][jb] = __builtin_amdgcn_mfma_f32_16x16x32_bf16(af, bfr[jb], acc1[ia][jb], 0, 0, 0);
        }
      }
    }

    // ===== z = BN2(acc1) -> zLds + halo publish =====
    {
      const int step = (dil <= 64) ? 1 : 2;
      const int w = (dil < 64) ? dil : 64;
      const int rdL = xt - step, rdR = xt + step;
      const bool pubL = (rdL >= 0);
      const bool pubR = (rdR <= 12);
      const bool scL = pubL && ((rdL >= 7) != (xt >= 7));  // cross-XCD
      const bool scR = pubR && ((rdR >= 7) != (xt >= 7));
      unsigned short* zgl = p.zg + ((size_t)(layer * NBLK + lg)) * (64 * 512);
#pragma unroll
      for (int ia = 0; ia < 2; ++ia) {
        int db = wv * 32 + ia * 16 + kg * 4;
        float4 s2v = *(const float4*)(s2p + db);
        float4 o2v = *(const float4*)(o2p + db);
#pragma unroll
        for (int jb = 0; jb < 4; ++jb) {
          int l = jb * 16 + frow;
          shortx4 pk;
          pk[0] = f2bf(fmaf(acc1[ia][jb][0], s2v.x, o2v.x));
          pk[1] = f2bf(fmaf(acc1[ia][jb][1], s2v.y, o2v.y));
          pk[2] = f2bf(fmaf(acc1[ia][jb][2], s2v.z, o2v.z));
          pk[3] = f2bf(fmaf(acc1[ia][jb][3], s2v.w, o2v.w));
          *(shortx4*)(ZsRaw + (db >> 3) * SG + l * 16 + (kg & 1) * 8) = pk;
          bool needL = pubL && (l < w);
          bool needR = pubR && (l >= 64 - w);
          if (needL || needR) {
            unsigned long long u;
            __builtin_memcpy(&u, &pk, 8);
            unsigned long long* dst = (unsigned long long*)(zgl + (size_t)l * 512 + db);
            if ((needL && scL) || (needR && scR))
              __hip_atomic_store(dst, u, __ATOMIC_RELAXED, __HIP_MEMORY_SCOPE_AGENT);
            else
              *dst = u;
          }
        }
      }
    }
    __syncthreads();
    if (tid == 0)
      __hip_atomic_store(&p.ct[lg], (unsigned)(layer + 1),
                         __ATOMIC_RELAXED, __HIP_MEMORY_SCOPE_AGENT);

    // ===== B3 = BN3(dconv(z)) two-pass: interior first, edges after spin =====
    {
      const float* wdp = p.wd + (size_t)layer * D_ * 3 + lane * 24;
      float4 wq[6];
#pragma unroll
      for (int q = 0; q < 6; ++q) wq[q] = *(const float4*)(wdp + 4 * q);
      float4 s3a = *(const float4*)(s3p + lane * 8), s3b = *(const float4*)(s3p + lane * 8 + 4);
      float4 o3a = *(const float4*)(o3p + lane * 8), o3b = *(const float4*)(o3p + lane * 8 + 4);
      const unsigned short* zlay = p.zg + (size_t)layer * NBLK * (64 * 512);

#pragma unroll
      for (int pass = 0; pass < 2; ++pass) {
        if (pass == 1) {
          if (tid == 0) {
            int step = (dil <= 64) ? 1 : 2;
            for (int s = -1; s <= 1; s += 2) {
              int xx = xt + s * step;
              if (xx < 0 || xx > 12) continue;
              const unsigned* c2 = &p.ct[n * 13 + xx];
              while (__hip_atomic_load((unsigned*)c2, __ATOMIC_RELAXED, __HIP_MEMORY_SCOPE_AGENT)
                     <= (unsigned)layer)
                __builtin_amdgcn_s_sleep(1);
            }
          }
          __syncthreads();
        }
#pragma unroll
        for (int r = 0; r < 4; ++r) {
          int row = wv * 4 + r;
          int gcol = l0 + row;
          int gl = gcol - dil, gr = gcol + dil;
          bool remL = (gl >= 0) && (gl < l0);
          bool remR = (gr < L_) && (gr >= l0 + 64);
          bool isRem = remL || remR;
          if ((pass == 0) == isRem) continue;
          bf16x8 zc = *(bf16x8*)(ZsRaw + lane * SG + row * 16);
          bf16x8 zl = {0, 0, 0, 0, 0, 0, 0, 0};
          bf16x8 zr = {0, 0, 0, 0, 0, 0, 0, 0};
          if (gl >= 0) {
            if (!remL) zl = *(bf16x8*)(ZsRaw + lane * SG + (gl - l0) * 16);
            else zl = *(const bf16x8*)(zlay + ((size_t)(n * 13 + (gl >> 6))) * (64 * 512)
                                       + (size_t)(gl & 63) * 512 + lane * 8);
          }
          if (gr < L_) {
            if (!remR) zr = *(bf16x8*)(ZsRaw + lane * SG + (gr - l0) * 16);
            else zr = *(const bf16x8*)(zlay + ((size_t)(n * 13 + (gr >> 6))) * (64 * 512)
                                       + (size_t)(gr & 63) * 512 + lane * 8);
          }
          bf16x8 pb;
#pragma unroll
          for (int j = 0; j < 8; ++j) {
            float w0 = wq[(3 * j + 0) >> 2][(3 * j + 0) & 3];
            float w1v = wq[(3 * j + 1) >> 2][(3 * j + 1) & 3];
            float w2v = wq[(3 * j + 2) >> 2][(3 * j + 2) & 3];
            float m = bf2f(zc[j]) * w1v;
            m = fmaf(bf2f(zl[j]), w0, m);
            m = fmaf(bf2f(zr[j]), w2v, m);
            float s3v = (j < 4) ? s3a[j] : s3b[j - 4];
            float o3v = (j < 4) ? o3a[j] : o3b[j - 4];
            pb[j] = f2bf(fmaf(m, s3v, o3v));
          }
          *(bf16x8*)(BsRaw + lane * SG + row * 16) = pb;
        }
      }
    }
    __syncthreads();

    // ===== stage2 MFMA: acc2[c 256][l 64] ; wave owns 16 c rows ; hreg += =====
    {
      f32x4 acc2[4] = {};
      const short* W2 = p.w2b + (size_t)layer * C_ * D_;
#pragma unroll
      for (int k0 = 0; k0 < 16; ++k0) {
        int kb = k0 * 32 + kg * 8;
        bf16x8 bfr[4];
#pragma unroll
        for (int jb = 0; jb < 4; ++jb)
          bfr[jb] = *(bf16x8*)(BsRaw + (k0 * 4 + kg) * SG + (jb * 16 + frow) * 16);
        bf16x8 af = *(const bf16x8*)(W2 + (size_t)(wv * 16 + frow) * D_ + kb);
#pragma unroll
        for (int jb = 0; jb < 4; ++jb)
          acc2[jb] = __builtin_amdgcn_mfma_f32_16x16x32_bf16(af, bfr[jb], acc2[jb], 0, 0, 0);
      }
#pragma unroll
      for (int jb = 0; jb < 4; ++jb)
#pragma unroll
        for (int jj = 0; jj < 4; ++jj)
          hreg[jb][jj] += acc2[jb][jj];
    }
    __syncthreads();   // Bs reads done before next layer's B1 writes
  }

  // ---------------- mask: y = xe * sigmoid(h) -> yb [n][l][c] ----------------
  {
    float* yn = p.yb + (size_t)n * ((size_t)L_ * C_);
    const int cb = wv * 16 + kg * 4;
#pragma unroll
    for (int jb = 0; jb < 4; ++jb) {
      int gl = l0 + jb * 16 + frow;
      if (gl < L_) {
        float v[4];
#pragma unroll
        for (int jj = 0; jj < 4; ++jj)
          v[jj] = xer[jb][jj] / (1.f + expf(-hreg[jb][jj]));
        unsigned long long u0, u1;
        __builtin_memcpy(&u0, &v[0], 8);
        __builtin_memcpy(&u1, &v[2], 8);
        unsigned long long* dst = (unsigned long long*)(yn + (size_t)gl * C_ + cb);
        __hip_atomic_store(dst + 0, u0, __ATOMIC_RELAXED, __HIP_MEMORY_SCOPE_AGENT);
        __hip_atomic_store(dst + 1, u1, __ATOMIC_RELAXED, __HIP_MEMORY_SCOPE_AGENT);
      }
    }
  }
  bar_heavy(p.gbar, NBLK, tid);

  // ---------------- decoder ----------------
  for (int idx = gtid; idx < NBATCH * T_; idx += NTH_G) {
    int t = idx % T_;
    int nn = idx / T_;
    int tt = t + FK_;
    int lq = tt / 10;      // in [2, 801]
    int k0 = tt % 10;
    const float* y0 = p.yb + (size_t)nn * ((size_t)L_ * C_) + (size_t)lq * C_;
    const float* y1 = y0 - C_;
    float acc = 0.f;
#pragma unroll 8
    for (int c = 0; c < C_; c++) {
      const float* wr2 = p.w_dec + c * FK_;
      acc = fmaf(y0[c], wr2[k0], acc);
      acc = fmaf(y1[c], wr2[k0 + 10], acc);
    }
    p.out[idx] = acc;
  }
}

extern "C" void kernel_launch(void* const* d_in, const int* in_sizes, int n_in,
                              void* d_out, int out_size, void* d_ws, size_t ws_size,
                              hipStream_t stream) {
  KParams hp;
  hp.x     = (const float*)d_in[0];
  hp.w_enc = (const float*)d_in[1];
  hp.w1    = (const float*)d_in[2];
  hp.wd    = (const float*)d_in[3];
  hp.w2    = (const float*)d_in[4];
  hp.w_dec = (const float*)d_in[5];
  hp.g1 = (const float*)d_in[6];  hp.bb1 = (const float*)d_in[7];
  hp.m1 = (const float*)d_in[8];  hp.v1  = (const float*)d_in[9];
  hp.g2 = (const float*)d_in[10]; hp.bb2 = (const float*)d_in[11];
  hp.m2 = (const float*)d_in[12]; hp.v2  = (const float*)d_in[13];
  hp.g3 = (const float*)d_in[14]; hp.bb3 = (const float*)d_in[15];
  hp.m3 = (const float*)d_in[16]; hp.v3  = (const float*)d_in[17];
  hp.out = (float*)d_out;

  char* cur = (char*)d_ws;
  auto take = [&](size_t bytes) { char* r = cur; cur += (bytes + 255) & ~(size_t)255; return r; };
  hp.gbar = (Bar*)take(256);
  hp.ct   = (unsigned*)take(NBLK * 4);
  hp.s1 = (float*)take(NB_ * C_ * 4);
  hp.o1 = (float*)take(NB_ * C_ * 4);
  hp.s2 = (float*)take(NB_ * D_ * 4);
  hp.o2 = (float*)take(NB_ * D_ * 4);
  hp.s3 = (float*)take(NB_ * D_ * 4);
  hp.o3 = (float*)take(NB_ * D_ * 4);
  hp.yb  = (float*)take((size_t)NBATCH * L_ * C_ * 4);
  hp.w1b = (short*)take((size_t)NB_ * D_ * C_ * 2);
  hp.w2b = (short*)take((size_t)NB_ * D_ * C_ * 2);
  hp.zg  = (unsigned short*)take((size_t)NB_ * NBLK * 64 * 512 * 2);   // 109 MB

  hipMemsetAsync(d_ws, 0, 1024, stream);   // gbar + ct
  prep_kernel<<<dim3(1024), dim3(256), 0, stream>>>(hp);
  tasnet_fused<<<dim3(NBLK), dim3(NTHR), 0, stream>>>(hp);
}

// Round 16
// 748.921 us; speedup vs baseline: 1.2620x; 1.2620x over previous
//
#include <hip/hip_runtime.h>
#include <cstddef>
#include <cstring>

#define T_     8000
#define L_     803
#define C_     256
#define D_     512
#define NB_    32
#define FK_    20
#define NBATCH 4
#define EPS_   1e-5f

#define NBLK   208           // 52 strips (13 l-tiles x 4 batch) x 4 slices
#define NTHR   512           // 8 waves
#define NTH_G  (NBLK * NTHR)
#define SG     1040          // LDS group stride bytes: 64 cols * 16B + 16B pad

typedef __attribute__((ext_vector_type(8))) short bf16x8;
typedef __attribute__((ext_vector_type(4))) short shortx4;
typedef __attribute__((ext_vector_type(4))) float f32x4;
typedef unsigned long long u64;

__device__ __forceinline__ short f2bf(float x) {
  unsigned u = __float_as_uint(x);
  u += 0x7FFF + ((u >> 16) & 1);   // RNE
  return (short)(u >> 16);
}
__device__ __forceinline__ float bf2f(short u) {
  return __uint_as_float(((unsigned)(unsigned short)u) << 16);
}

__device__ __forceinline__ u64 aload8(const void* p) {
  return __hip_atomic_load((const u64*)p, __ATOMIC_RELAXED, __HIP_MEMORY_SCOPE_AGENT);
}
__device__ __forceinline__ void astore8(void* p, u64 v) {
  __hip_atomic_store((u64*)p, v, __ATOMIC_RELAXED, __HIP_MEMORY_SCOPE_AGENT);
}

struct __align__(64) Bar { unsigned cnt; unsigned phase; unsigned pad[14]; };

__device__ __forceinline__ void bar_heavy(Bar* b, unsigned nblk, int tid) {
  __syncthreads();
  if (tid == 0) {
    __threadfence();
    unsigned ph = __hip_atomic_load(&b->phase, __ATOMIC_RELAXED, __HIP_MEMORY_SCOPE_AGENT);
    unsigned prev = __hip_atomic_fetch_add(&b->cnt, 1u, __ATOMIC_RELAXED, __HIP_MEMORY_SCOPE_AGENT);
    if (prev == nblk - 1) {
      __hip_atomic_store(&b->cnt, 0u, __ATOMIC_RELAXED, __HIP_MEMORY_SCOPE_AGENT);
      __hip_atomic_store(&b->phase, ph + 1u, __ATOMIC_RELEASE, __HIP_MEMORY_SCOPE_AGENT);
    } else {
      while (__hip_atomic_load(&b->phase, __ATOMIC_RELAXED, __HIP_MEMORY_SCOPE_AGENT) == ph)
        __builtin_amdgcn_s_sleep(2);
    }
    __threadfence();
  }
  __syncthreads();
}

struct KParams {
  const float *x, *w_enc, *w1, *wd, *w2, *w_dec;
  const float *g1, *bb1, *m1, *v1;
  const float *g2, *bb2, *m2, *v2;
  const float *g3, *bb3, *m3, *v3;
  float *out;
  float *s1, *o1, *s2, *o2, *s3, *o3;
  float *yb;                  // y [n][l][c] f32
  short *w1b, *w2b;           // bf16 weights
  unsigned short *zg;         // z: [2 buf][52 strip][64 col][512 d] bf16
  float *hb;                  // h: [2 buf][n][l][c 256] f32
  unsigned *ct;               // per-block monotone counter [208]
  Bar *gbar;
};

// ---------- full-grid prep: BN fold + weight bf16 conversion ----------
__global__ __launch_bounds__(256) void prep_kernel(KParams p) {
  const int gtid = blockIdx.x * 256 + threadIdx.x;
  const int stride = gridDim.x * 256;
  for (int i = gtid; i < NB_ * C_; i += stride) {
    float s = p.g1[i] * rsqrtf(p.v1[i] + EPS_);
    p.s1[i] = s; p.o1[i] = p.bb1[i] - p.m1[i] * s;
  }
  for (int i = gtid; i < NB_ * D_; i += stride) {
    float s2 = p.g2[i] * rsqrtf(p.v2[i] + EPS_);
    p.s2[i] = s2; p.o2[i] = p.bb2[i] - p.m2[i] * s2;
    float s3 = p.g3[i] * rsqrtf(p.v3[i] + EPS_);
    p.s3[i] = s3; p.o3[i] = p.bb3[i] - p.m3[i] * s3;
  }
  for (int i = gtid; i < NB_ * D_ * C_ / 4; i += stride) {
    float4 a = ((const float4*)p.w1)[i];
    float4 b = ((const float4*)p.w2)[i];
    shortx4 sa, sb;
    sa[0] = f2bf(a.x); sa[1] = f2bf(a.y); sa[2] = f2bf(a.z); sa[3] = f2bf(a.w);
    sb[0] = f2bf(b.x); sb[1] = f2bf(b.y); sb[2] = f2bf(b.z); sb[3] = f2bf(b.w);
    *(shortx4*)&p.w1b[4 * i] = sa;
    *(shortx4*)&p.w2b[4 * i] = sb;
  }
}

__global__ __launch_bounds__(NTHR) void tasnet_fused(KParams p) {
  const int tid = threadIdx.x;
  const int bid = blockIdx.x;

  const int g = bid >> 2, y = bid & 3;        // strip-group, slice
  const int xt = g % 13, n = g / 13;
  const int l0 = xt * 64;

  const int lane = tid & 63, wv = tid >> 6;   // 8 waves
  const int frow = lane & 15, kg = lane >> 4;
  const int cw = wv & 3;                      // c-subgroup  (stage2/hreg)
  const int ch = wv >> 2;                     // col-half    (stage2/hreg)
  const int cbase = y * 64 + cw * 16 + kg * 4;

  __shared__ __align__(16) char BsRaw[64 * SG];   // 66.5 KB  [kgrp][col][16B]
  __shared__ __align__(16) char ZsRaw[64 * SG];   // 66.5 KB  [dgrp][col][16B]

  const size_t HB = (size_t)NBATCH * L_ * C_;     // floats per h buffer
  const size_t ZB = (size_t)52 * 64 * 512;        // shorts per z buffer

  // ---------------- encoder -> hreg (stage2-fragment layout) ----------------
  // element (jb,jj): c = cbase+jj ; l = l0 + ch*32 + jb*16 + frow  (jb 0..1)
  f32x4 hreg[2], xer[2];
  {
    const float* xn_ = p.x + (size_t)n * T_;
#pragma unroll
    for (int jb = 0; jb < 2; ++jb) {
      int gl = l0 + ch * 32 + jb * 16 + frow;
      int t0 = gl * 10 - 20;
      float xw[FK_];
#pragma unroll
      for (int k = 0; k < FK_; ++k) {
        int t = t0 + k;
        xw[k] = (t >= 0 && t < T_) ? xn_[t] : 0.f;
      }
#pragma unroll
      for (int jj = 0; jj < 4; ++jj) {
        const float* w = p.w_enc + (cbase + jj) * FK_;
        float acc = 0.f;
#pragma unroll
        for (int k = 0; k < FK_; ++k) acc = fmaf(xw[k], w[k], acc);
        hreg[jb][jj] = acc;
        xer[jb][jj] = acc;
      }
    }
    // publish h0 (own c-slice) to h buffer 0
    float* h0 = p.hb + (size_t)n * (L_ * C_);
#pragma unroll
    for (int jb = 0; jb < 2; ++jb) {
      int gl = l0 + ch * 32 + jb * 16 + frow;
      if (gl < L_) {
        float tmp[4] = {hreg[jb][0], hreg[jb][1], hreg[jb][2], hreg[jb][3]};
        u64 u0, u1;
        __builtin_memcpy(&u0, &tmp[0], 8);
        __builtin_memcpy(&u1, &tmp[2], 8);
        float* dst = h0 + (size_t)gl * C_ + cbase;
        astore8(dst, u0);
        astore8(dst + 2, u1);
      }
    }
  }
  __syncthreads();
  if (tid == 0)
    __hip_atomic_store(&p.ct[bid], 2u, __ATOMIC_RELAXED, __HIP_MEMORY_SCOPE_AGENT);

  // ---------------- 32 residual blocks ----------------
  for (int layer = 0; layer < NB_; ++layer) {
    const int dil = 1 << (layer & 7);
    const int step = (dil <= 64) ? 1 : 2;
    const float* s1p = p.s1 + layer * C_;
    const float* o1p = p.o1 + layer * C_;
    const float* s2p = p.s2 + layer * D_;
    const float* o2p = p.o2 + layer * D_;
    const float* s3p = p.s3 + layer * D_;
    const float* o3p = p.o3 + layer * D_;
    const float* hb_cur = p.hb + (size_t)(layer & 1) * HB + (size_t)n * (L_ * C_);
    float* hb_nxt = p.hb + (size_t)((layer + 1) & 1) * HB + (size_t)n * (L_ * C_);
    unsigned short* zstrip = p.zg + (size_t)(layer & 1) * ZB + (size_t)(n * 13 + xt) * (64 * 512);

    // ===== B1 own slice: BN1(hreg) -> Bs =====
    {
      float4 s1v = *(const float4*)(s1p + cbase);
      float4 o1v = *(const float4*)(o1p + cbase);
#pragma unroll
      for (int jb = 0; jb < 2; ++jb) {
        int col = ch * 32 + jb * 16 + frow;
        shortx4 pk;
        pk[0] = f2bf(fmaf(hreg[jb][0], s1v.x, o1v.x));
        pk[1] = f2bf(fmaf(hreg[jb][1], s1v.y, o1v.y));
        pk[2] = f2bf(fmaf(hreg[jb][2], s1v.z, o1v.z));
        pk[3] = f2bf(fmaf(hreg[jb][3], s1v.w, o1v.w));
        *(shortx4*)(BsRaw + (cbase >> 3) * SG + col * 16 + (kg & 1) * 8) = pk;
      }
    }
    // spin: siblings' h(layer) published (ctB >= 2+2*layer)
    if (wv == 0 && lane < 3) {
      int idx = g * 4 + ((y + 1 + lane) & 3);
      unsigned tgt = 2u + 2u * (unsigned)layer;
      while (__hip_atomic_load(&p.ct[idx], __ATOMIC_RELAXED, __HIP_MEMORY_SCOPE_AGENT) < tgt)
        __builtin_amdgcn_s_sleep(1);
    }
    __syncthreads();
    // ===== B1 sibling slices: hb -> BN1 -> Bs =====
    {
      int col = tid >> 3, k8 = tid & 7;
      int gl = l0 + col;
      bool lv = gl < L_;
#pragma unroll
      for (int s = 1; s < 4; ++s) {
        int sc = ((y + s) & 3) * 64 + k8 * 8;
        float hv[8] = {};
        if (lv) {
          const float* src = hb_cur + (size_t)gl * C_ + sc;
          u64 a0 = aload8(src), a1 = aload8(src + 2), a2 = aload8(src + 4), a3 = aload8(src + 6);
          __builtin_memcpy(&hv[0], &a0, 8); __builtin_memcpy(&hv[2], &a1, 8);
          __builtin_memcpy(&hv[4], &a2, 8); __builtin_memcpy(&hv[6], &a3, 8);
        }
        bf16x8 pk;
#pragma unroll
        for (int j = 0; j < 8; ++j)
          pk[j] = f2bf(fmaf(hv[j], s1p[sc + j], o1p[sc + j]));
        *(bf16x8*)(BsRaw + (sc >> 3) * SG + col * 16) = pk;
      }
    }
    __syncthreads();

    // ===== stage1 MFMA: d-slice [y*128,+128) x cols 64, K=256 =====
    f32x4 acc1[4] = {};
    {
      const short* W1 = p.w1b + (size_t)layer * D_ * C_ + (size_t)(y * 128 + wv * 16 + frow) * C_;
#pragma unroll
      for (int k0 = 0; k0 < 8; ++k0) {
        int kb = k0 * 32 + kg * 8;
        bf16x8 af = *(const bf16x8*)(W1 + kb);
#pragma unroll
        for (int jb = 0; jb < 4; ++jb) {
          bf16x8 bfr = *(bf16x8*)(BsRaw + (k0 * 4 + kg) * SG + (jb * 16 + frow) * 16);
          acc1[jb] = __builtin_amdgcn_mfma_f32_16x16x32_bf16(af, bfr, acc1[jb], 0, 0, 0);
        }
      }
    }
    // ===== z = BN2(acc1) -> Zs + sc1 publish (full own slice) =====
    {
      int db = y * 128 + wv * 16 + kg * 4;
      float4 s2v = *(const float4*)(s2p + db);
      float4 o2v = *(const float4*)(o2p + db);
#pragma unroll
      for (int jb = 0; jb < 4; ++jb) {
        int col = jb * 16 + frow;
        shortx4 pk;
        pk[0] = f2bf(fmaf(acc1[jb][0], s2v.x, o2v.x));
        pk[1] = f2bf(fmaf(acc1[jb][1], s2v.y, o2v.y));
        pk[2] = f2bf(fmaf(acc1[jb][2], s2v.z, o2v.z));
        pk[3] = f2bf(fmaf(acc1[jb][3], s2v.w, o2v.w));
        *(shortx4*)(ZsRaw + (db >> 3) * SG + col * 16 + (kg & 1) * 8) = pk;
        u64 u;
        __builtin_memcpy(&u, &pk, 8);
        astore8(zstrip + (size_t)col * 512 + db, u);
      }
    }
    __syncthreads();
    if (tid == 0)
      __hip_atomic_store(&p.ct[bid], (unsigned)(2 * layer + 3),
                         __ATOMIC_RELAXED, __HIP_MEMORY_SCOPE_AGENT);
    // spin: siblings (z slices) + neighbor strips (halo), ct >= 2*layer+3
    if (wv == 0 && lane < 11) {
      int idx = -1;
      if (lane < 3) idx = g * 4 + ((y + 1 + lane) & 3);
      else {
        int k = lane - 3;
        int xn2 = xt + ((k >> 2) ? step : -step);
        if (xn2 >= 0 && xn2 <= 12) idx = (n * 13 + xn2) * 4 + (k & 3);
      }
      if (idx >= 0) {
        unsigned tgt = (unsigned)(2 * layer + 3);
        while (__hip_atomic_load(&p.ct[idx], __ATOMIC_RELAXED, __HIP_MEMORY_SCOPE_AGENT) < tgt)
          __builtin_amdgcn_s_sleep(1);
      }
    }
    __syncthreads();
    // ===== sibling z slices -> Zs =====
    {
      int col = tid >> 3, k8 = tid & 7;
#pragma unroll
      for (int s = 1; s < 4; ++s) {
        int sd0g = ((y + s) & 3) * 16;    // dgrp base of sibling slice
#pragma unroll
        for (int q = 0; q < 2; ++q) {
          int dg = sd0g + k8 * 2 + q;
          const unsigned short* src = zstrip + (size_t)col * 512 + dg * 8;
          u64 a = aload8(src);
          u64 b = aload8(src + 4);
          char* dst = ZsRaw + dg * SG + col * 16;
          __builtin_memcpy(dst, &a, 8);
          __builtin_memcpy(dst + 8, &b, 8);
        }
      }
    }
    __syncthreads();

    // ===== B3 = BN3(dconv(z)) -> Bs ; wave: 8 rows, lane owns 8 d =====
    {
      const float* wdp = p.wd + (size_t)layer * D_ * 3 + lane * 24;
      float4 wq[6];
#pragma unroll
      for (int q = 0; q < 6; ++q) wq[q] = *(const float4*)(wdp + 4 * q);
      float4 s3a = *(const float4*)(s3p + lane * 8), s3b = *(const float4*)(s3p + lane * 8 + 4);
      float4 o3a = *(const float4*)(o3p + lane * 8), o3b = *(const float4*)(o3p + lane * 8 + 4);
      const unsigned short* zlay = p.zg + (size_t)(layer & 1) * ZB;
#pragma unroll
      for (int rr = 0; rr < 8; ++rr) {
        int row = wv * 8 + rr;
        int gcol = l0 + row;
        bf16x8 zc = *(bf16x8*)(ZsRaw + lane * SG + row * 16);
        bf16x8 zl = {0, 0, 0, 0, 0, 0, 0, 0};
        bf16x8 zr = {0, 0, 0, 0, 0, 0, 0, 0};
        int gl2 = gcol - dil, gr2 = gcol + dil;
        if (gl2 >= 0) {
          if (gl2 >= l0) zl = *(bf16x8*)(ZsRaw + lane * SG + (gl2 - l0) * 16);
          else {
            const unsigned short* src = zlay + (size_t)(n * 13 + (gl2 >> 6)) * (64 * 512)
                                        + (size_t)(gl2 & 63) * 512 + lane * 8;
            u64 a = aload8(src), b = aload8(src + 4);
            __builtin_memcpy(&zl, &a, 8);
            __builtin_memcpy(((char*)&zl) + 8, &b, 8);
          }
        }
        if (gr2 < L_) {
          if (gr2 < l0 + 64) zr = *(bf16x8*)(ZsRaw + lane * SG + (gr2 - l0) * 16);
          else {
            const unsigned short* src = zlay + (size_t)(n * 13 + (gr2 >> 6)) * (64 * 512)
                                        + (size_t)(gr2 & 63) * 512 + lane * 8;
            u64 a = aload8(src), b = aload8(src + 4);
            __builtin_memcpy(&zr, &a, 8);
            __builtin_memcpy(((char*)&zr) + 8, &b, 8);
          }
        }
        bf16x8 pb;
#pragma unroll
        for (int j = 0; j < 8; ++j) {
          float w0 = wq[(3 * j + 0) >> 2][(3 * j + 0) & 3];
          float w1v = wq[(3 * j + 1) >> 2][(3 * j + 1) & 3];
          float w2v = wq[(3 * j + 2) >> 2][(3 * j + 2) & 3];
          float m = bf2f(zc[j]) * w1v;
          m = fmaf(bf2f(zl[j]), w0, m);
          m = fmaf(bf2f(zr[j]), w2v, m);
          float s3v = (j < 4) ? s3a[j] : s3b[j - 4];
          float o3v = (j < 4) ? o3a[j] : o3b[j - 4];
          pb[j] = f2bf(fmaf(m, s3v, o3v));
        }
        *(bf16x8*)(BsRaw + lane * SG + row * 16) = pb;
      }
    }
    __syncthreads();

    // ===== stage2 MFMA: c-slice [y*64,+64) x cols 64, K=512 ; hreg += =====
    {
      f32x4 acc2[2] = {};
      const short* W2 = p.w2b + (size_t)layer * C_ * D_ + (size_t)(y * 64 + cw * 16 + frow) * D_;
#pragma unroll
      for (int k0 = 0; k0 < 16; ++k0) {
        int kb = k0 * 32 + kg * 8;
        bf16x8 af = *(const bf16x8*)(W2 + kb);
#pragma unroll
        for (int jb = 0; jb < 2; ++jb) {
          int col = ch * 32 + jb * 16 + frow;
          bf16x8 bfr = *(bf16x8*)(BsRaw + (k0 * 4 + kg) * SG + col * 16);
          acc2[jb] = __builtin_amdgcn_mfma_f32_16x16x32_bf16(af, bfr, acc2[jb], 0, 0, 0);
        }
      }
#pragma unroll
      for (int jb = 0; jb < 2; ++jb)
#pragma unroll
        for (int jj = 0; jj < 4; ++jj)
          hreg[jb][jj] += acc2[jb][jj];
    }
    // publish h' (own c-slice) for next layer's B1
#pragma unroll
    for (int jb = 0; jb < 2; ++jb) {
      int gl = l0 + ch * 32 + jb * 16 + frow;
      if (gl < L_) {
        float tmp[4] = {hreg[jb][0], hreg[jb][1], hreg[jb][2], hreg[jb][3]};
        u64 u0, u1;
        __builtin_memcpy(&u0, &tmp[0], 8);
        __builtin_memcpy(&u1, &tmp[2], 8);
        float* dst = hb_nxt + (size_t)gl * C_ + cbase;
        astore8(dst, u0);
        astore8(dst + 2, u1);
      }
    }
    __syncthreads();
    if (tid == 0)
      __hip_atomic_store(&p.ct[bid], (unsigned)(2 * layer + 4),
                         __ATOMIC_RELAXED, __HIP_MEMORY_SCOPE_AGENT);
  }

  // ---------------- mask: y = xe * sigmoid(h) -> yb (own fragment) ----------
  {
    float* yn = p.yb + (size_t)n * ((size_t)L_ * C_);
#pragma unroll
    for (int jb = 0; jb < 2; ++jb) {
      int gl = l0 + ch * 32 + jb * 16 + frow;
      if (gl < L_) {
        float4 v;
        v.x = xer[jb][0] / (1.f + expf(-hreg[jb][0]));
        v.y = xer[jb][1] / (1.f + expf(-hreg[jb][1]));
        v.z = xer[jb][2] / (1.f + expf(-hreg[jb][2]));
        v.w = xer[jb][3] / (1.f + expf(-hreg[jb][3]));
        *(float4*)(yn + (size_t)gl * C_ + cbase) = v;
      }
    }
  }
  bar_heavy(p.gbar, NBLK, tid);

  // ---------------- decoder ----------------
  for (int idx = bid * NTHR + tid; idx < NBATCH * T_; idx += NTH_G) {
    int t = idx % T_;
    int nn = idx / T_;
    int tt = t + FK_;
    int lq = tt / 10;      // in [2, 801]
    int k0 = tt % 10;
    const float* y0 = p.yb + (size_t)nn * ((size_t)L_ * C_) + (size_t)lq * C_;
    const float* y1 = y0 - C_;
    float acc = 0.f;
#pragma unroll 8
    for (int c = 0; c < C_; c++) {
      const float* wr2 = p.w_dec + c * FK_;
      acc = fmaf(y0[c], wr2[k0], acc);
      acc = fmaf(y1[c], wr2[k0 + 10], acc);
    }
    p.out[idx] = acc;
  }
}

extern "C" void kernel_launch(void* const* d_in, const int* in_sizes, int n_in,
                              void* d_out, int out_size, void* d_ws, size_t ws_size,
                              hipStream_t stream) {
  KParams hp;
  hp.x     = (const float*)d_in[0];
  hp.w_enc = (const float*)d_in[1];
  hp.w1    = (const float*)d_in[2];
  hp.wd    = (const float*)d_in[3];
  hp.w2    = (const float*)d_in[4];
  hp.w_dec = (const float*)d_in[5];
  hp.g1 = (const float*)d_in[6];  hp.bb1 = (const float*)d_in[7];
  hp.m1 = (const float*)d_in[8];  hp.v1  = (const float*)d_in[9];
  hp.g2 = (const float*)d_in[10]; hp.bb2 = (const float*)d_in[11];
  hp.m2 = (const float*)d_in[12]; hp.v2  = (const float*)d_in[13];
  hp.g3 = (const float*)d_in[14]; hp.bb3 = (const float*)d_in[15];
  hp.m3 = (const float*)d_in[16]; hp.v3  = (const float*)d_in[17];
  hp.out = (float*)d_out;

  char* cur = (char*)d_ws;
  auto take = [&](size_t bytes) { char* r = cur; cur += (bytes + 255) & ~(size_t)255; return r; };
  hp.gbar = (Bar*)take(256);
  hp.ct   = (unsigned*)take(NBLK * 4);
  hp.s1 = (float*)take(NB_ * C_ * 4);
  hp.o1 = (float*)take(NB_ * C_ * 4);
  hp.s2 = (float*)take(NB_ * D_ * 4);
  hp.o2 = (float*)take(NB_ * D_ * 4);
  hp.s3 = (float*)take(NB_ * D_ * 4);
  hp.o3 = (float*)take(NB_ * D_ * 4);
  hp.yb  = (float*)take((size_t)NBATCH * L_ * C_ * 4);
  hp.w1b = (short*)take((size_t)NB_ * D_ * C_ * 2);
  hp.w2b = (short*)take((size_t)NB_ * D_ * C_ * 2);
  hp.hb  = (float*)take(2 * (size_t)NBATCH * L_ * C_ * 4);      // 2 bufs
  hp.zg  = (unsigned short*)take(2 * (size_t)52 * 64 * 512 * 2); // 2 bufs

  hipMemsetAsync(d_ws, 0, 2048, stream);   // gbar + ct
  prep_kernel<<<dim3(1024), dim3(256), 0, stream>>>(hp);
  tasnet_fused<<<dim3(NBLK), dim3(NTHR), 0, stream>>>(hp);
}

// Round 17
// 626.675 us; speedup vs baseline: 1.5082x; 1.1951x over previous
//
#include <hip/hip_runtime.h>
#include <cstddef>
#include <cstring>

#define T_     8000
#define L_     803
#define C_     256
#define D_     512
#define NB_    32
#define FK_    20
#define NBATCH 4
#define EPS_   1e-5f

#define NVALID 208           // 52 strips x 4 slices (logical blocks)
#define NGRID  224           // physical grid; g>=52 exits early
#define NTHR   512           // 8 waves
#define SG     1040          // LDS group stride bytes: 64 cols * 16B + 16B pad

typedef __attribute__((ext_vector_type(8))) short bf16x8;
typedef __attribute__((ext_vector_type(4))) short shortx4;
typedef __attribute__((ext_vector_type(4))) float f32x4;
typedef unsigned long long u64;

__device__ __forceinline__ short f2bf(float x) {
  unsigned u = __float_as_uint(x);
  u += 0x7FFF + ((u >> 16) & 1);   // RNE
  return (short)(u >> 16);
}
__device__ __forceinline__ float bf2f(short u) {
  return __uint_as_float(((unsigned)(unsigned short)u) << 16);
}

__device__ __forceinline__ void astore8(void* p, u64 v) {
  __hip_atomic_store((u64*)p, v, __ATOMIC_RELAXED, __HIP_MEMORY_SCOPE_AGENT);
}

struct __align__(64) Bar { unsigned cnt; unsigned phase; unsigned pad[14]; };

__device__ __forceinline__ void bar_heavy(Bar* b, unsigned nblk, int tid) {
  __syncthreads();
  if (tid == 0) {
    __threadfence();
    unsigned ph = __hip_atomic_load(&b->phase, __ATOMIC_RELAXED, __HIP_MEMORY_SCOPE_AGENT);
    unsigned prev = __hip_atomic_fetch_add(&b->cnt, 1u, __ATOMIC_RELAXED, __HIP_MEMORY_SCOPE_AGENT);
    if (prev == nblk - 1) {
      __hip_atomic_store(&b->cnt, 0u, __ATOMIC_RELAXED, __HIP_MEMORY_SCOPE_AGENT);
      __hip_atomic_store(&b->phase, ph + 1u, __ATOMIC_RELEASE, __HIP_MEMORY_SCOPE_AGENT);
    } else {
      while (__hip_atomic_load(&b->phase, __ATOMIC_RELAXED, __HIP_MEMORY_SCOPE_AGENT) == ph)
        __builtin_amdgcn_s_sleep(2);
    }
    __threadfence();
  }
  __syncthreads();
}

struct KParams {
  const float *x, *w_enc, *w1, *wd, *w2, *w_dec;
  const float *g1, *bb1, *m1, *v1;
  const float *g2, *bb2, *m2, *v2;
  const float *g3, *bb3, *m3, *v3;
  float *out;
  float *s1, *o1, *s2, *o2, *s3, *o3;
  float *yb;                  // y [n][l][c] f32
  short *w1b, *w2b;           // bf16 weights
  unsigned short *zg;         // z: [32 buf][52 strip][64 col][512 d] bf16
  float *hb;                  // h: [33 buf][n][l][c 256] f32
  unsigned *ct;               // per-logical-block monotone counter [208]
  Bar *gbar;
};

// ---------- full-grid prep: BN fold + weight bf16 conversion ----------
__global__ __launch_bounds__(256) void prep_kernel(KParams p) {
  const int gtid = blockIdx.x * 256 + threadIdx.x;
  const int stride = gridDim.x * 256;
  for (int i = gtid; i < NB_ * C_; i += stride) {
    float s = p.g1[i] * rsqrtf(p.v1[i] + EPS_);
    p.s1[i] = s; p.o1[i] = p.bb1[i] - p.m1[i] * s;
  }
  for (int i = gtid; i < NB_ * D_; i += stride) {
    float s2 = p.g2[i] * rsqrtf(p.v2[i] + EPS_);
    p.s2[i] = s2; p.o2[i] = p.bb2[i] - p.m2[i] * s2;
    float s3 = p.g3[i] * rsqrtf(p.v3[i] + EPS_);
    p.s3[i] = s3; p.o3[i] = p.bb3[i] - p.m3[i] * s3;
  }
  for (int i = gtid; i < NB_ * D_ * C_ / 4; i += stride) {
    float4 a = ((const float4*)p.w1)[i];
    float4 b = ((const float4*)p.w2)[i];
    shortx4 sa, sb;
    sa[0] = f2bf(a.x); sa[1] = f2bf(a.y); sa[2] = f2bf(a.z); sa[3] = f2bf(a.w);
    sb[0] = f2bf(b.x); sb[1] = f2bf(b.y); sb[2] = f2bf(b.z); sb[3] = f2bf(b.w);
    *(shortx4*)&p.w1b[4 * i] = sa;
    *(shortx4*)&p.w2b[4 * i] = sb;
  }
}

__global__ __launch_bounds__(NTHR) void tasnet_fused(KParams p) {
  const int tid = threadIdx.x;
  const int bid = blockIdx.x;

  // XCD swizzle: siblings (same strip, y=0..3) share bid%8 -> same XCD L2.
  const int r8 = bid & 7, t8 = bid >> 3;
  const int g = (t8 >> 2) * 8 + r8;           // strip-group 0..55
  const int y = t8 & 3;                       // slice
  if (g >= 52) return;                        // 16 surplus blocks exit
  const int vid = g * 4 + y;                  // logical block id 0..207
  const int xt = g % 13, n = g / 13;
  const int l0 = xt * 64;

  const int lane = tid & 63, wv = tid >> 6;   // 8 waves
  const int frow = lane & 15, kg = lane >> 4;
  const int cw = wv & 3;                      // c-subgroup  (stage2/hreg)
  const int ch = wv >> 2;                     // col-half    (stage2/hreg)
  const int cbase = y * 64 + cw * 16 + kg * 4;

  __shared__ __align__(16) char BsRaw[64 * SG];   // 66.5 KB  [kgrp][col][16B]
  __shared__ __align__(16) char ZsRaw[64 * SG];   // 66.5 KB  [dgrp][col][16B]

  const size_t HB = (size_t)NBATCH * L_ * C_;     // floats per h buffer
  const size_t ZB = (size_t)52 * 64 * 512;        // shorts per z buffer

  // ---------------- encoder -> hreg (stage2-fragment layout) ----------------
  f32x4 hreg[2], xer[2];
  {
    const float* xn_ = p.x + (size_t)n * T_;
#pragma unroll
    for (int jb = 0; jb < 2; ++jb) {
      int gl = l0 + ch * 32 + jb * 16 + frow;
      int t0 = gl * 10 - 20;
      float xw[FK_];
#pragma unroll
      for (int k = 0; k < FK_; ++k) {
        int t = t0 + k;
        xw[k] = (t >= 0 && t < T_) ? xn_[t] : 0.f;
      }
#pragma unroll
      for (int jj = 0; jj < 4; ++jj) {
        const float* w = p.w_enc + (cbase + jj) * FK_;
        float acc = 0.f;
#pragma unroll
        for (int k = 0; k < FK_; ++k) acc = fmaf(xw[k], w[k], acc);
        hreg[jb][jj] = acc;
        xer[jb][jj] = acc;
      }
    }
    float* h0 = p.hb + (size_t)n * (L_ * C_);
#pragma unroll
    for (int jb = 0; jb < 2; ++jb) {
      int gl = l0 + ch * 32 + jb * 16 + frow;
      if (gl < L_) {
        float tmp[4] = {hreg[jb][0], hreg[jb][1], hreg[jb][2], hreg[jb][3]};
        u64 u0, u1;
        __builtin_memcpy(&u0, &tmp[0], 8);
        __builtin_memcpy(&u1, &tmp[2], 8);
        float* dst = h0 + (size_t)gl * C_ + cbase;
        astore8(dst, u0);
        astore8(dst + 2, u1);
      }
    }
  }
  __syncthreads();
  if (tid == 0)
    __hip_atomic_store(&p.ct[vid], 2u, __ATOMIC_RELAXED, __HIP_MEMORY_SCOPE_AGENT);

  // ---------------- 32 residual blocks ----------------
  for (int layer = 0; layer < NB_; ++layer) {
    const int dil = 1 << (layer & 7);
    const int step = (dil <= 64) ? 1 : 2;
    const float* s1p = p.s1 + layer * C_;
    const float* o1p = p.o1 + layer * C_;
    const float* s2p = p.s2 + layer * D_;
    const float* o2p = p.o2 + layer * D_;
    const float* s3p = p.s3 + layer * D_;
    const float* o3p = p.o3 + layer * D_;
    const float* hb_cur = p.hb + (size_t)layer * HB + (size_t)n * (L_ * C_);
    float* hb_nxt = p.hb + (size_t)(layer + 1) * HB + (size_t)n * (L_ * C_);
    unsigned short* zstrip = p.zg + (size_t)layer * ZB + (size_t)(n * 13 + xt) * (64 * 512);

    // ===== B1 own slice: BN1(hreg) -> Bs =====
    {
      float4 s1v = *(const float4*)(s1p + cbase);
      float4 o1v = *(const float4*)(o1p + cbase);
#pragma unroll
      for (int jb = 0; jb < 2; ++jb) {
        int col = ch * 32 + jb * 16 + frow;
        shortx4 pk;
        pk[0] = f2bf(fmaf(hreg[jb][0], s1v.x, o1v.x));
        pk[1] = f2bf(fmaf(hreg[jb][1], s1v.y, o1v.y));
        pk[2] = f2bf(fmaf(hreg[jb][2], s1v.z, o1v.z));
        pk[3] = f2bf(fmaf(hreg[jb][3], s1v.w, o1v.w));
        *(shortx4*)(BsRaw + (cbase >> 3) * SG + col * 16 + (kg & 1) * 8) = pk;
      }
    }
    // spin: siblings' h(layer) published (ct >= 2+2*layer)
    if (wv == 0 && lane < 3) {
      int idx = g * 4 + ((y + 1 + lane) & 3);
      unsigned tgt = 2u + 2u * (unsigned)layer;
      while (__hip_atomic_load(&p.ct[idx], __ATOMIC_RELAXED, __HIP_MEMORY_SCOPE_AGENT) < tgt)
        __builtin_amdgcn_s_sleep(1);
    }
    __syncthreads();
    // ===== B1 sibling slices: hb (normal cached loads) -> BN1 -> Bs =====
    {
      int col = tid >> 3, k8 = tid & 7;
      int gl = l0 + col;
      bool lv = gl < L_;
#pragma unroll
      for (int s = 1; s < 4; ++s) {
        int sc = ((y + s) & 3) * 64 + k8 * 8;
        float hv[8] = {};
        if (lv) {
          const float* src = hb_cur + (size_t)gl * C_ + sc;
          float4 a0 = *(const float4*)(src);
          float4 a1 = *(const float4*)(src + 4);
          hv[0] = a0.x; hv[1] = a0.y; hv[2] = a0.z; hv[3] = a0.w;
          hv[4] = a1.x; hv[5] = a1.y; hv[6] = a1.z; hv[7] = a1.w;
        }
        bf16x8 pk;
#pragma unroll
        for (int j = 0; j < 8; ++j)
          pk[j] = f2bf(fmaf(hv[j], s1p[sc + j], o1p[sc + j]));
        *(bf16x8*)(BsRaw + (sc >> 3) * SG + col * 16) = pk;
      }
    }
    __syncthreads();

    // ===== stage1 MFMA: d-slice [y*128,+128) x cols 64, K=256 =====
    f32x4 acc1[4] = {};
    {
      const short* W1 = p.w1b + (size_t)layer * D_ * C_ + (size_t)(y * 128 + wv * 16 + frow) * C_;
#pragma unroll
      for (int k0 = 0; k0 < 8; ++k0) {
        int kb = k0 * 32 + kg * 8;
        bf16x8 af = *(const bf16x8*)(W1 + kb);
#pragma unroll
        for (int jb = 0; jb < 4; ++jb) {
          bf16x8 bfr = *(bf16x8*)(BsRaw + (k0 * 4 + kg) * SG + (jb * 16 + frow) * 16);
          acc1[jb] = __builtin_amdgcn_mfma_f32_16x16x32_bf16(af, bfr, acc1[jb], 0, 0, 0);
        }
      }
    }
    // ===== z = BN2(acc1) -> Zs + sc1 publish (full own slice) =====
    {
      int db = y * 128 + wv * 16 + kg * 4;
      float4 s2v = *(const float4*)(s2p + db);
      float4 o2v = *(const float4*)(o2p + db);
#pragma unroll
      for (int jb = 0; jb < 4; ++jb) {
        int col = jb * 16 + frow;
        shortx4 pk;
        pk[0] = f2bf(fmaf(acc1[jb][0], s2v.x, o2v.x));
        pk[1] = f2bf(fmaf(acc1[jb][1], s2v.y, o2v.y));
        pk[2] = f2bf(fmaf(acc1[jb][2], s2v.z, o2v.z));
        pk[3] = f2bf(fmaf(acc1[jb][3], s2v.w, o2v.w));
        *(shortx4*)(ZsRaw + (db >> 3) * SG + col * 16 + (kg & 1) * 8) = pk;
        u64 u;
        __builtin_memcpy(&u, &pk, 8);
        astore8(zstrip + (size_t)col * 512 + db, u);
      }
    }
    __syncthreads();
    if (tid == 0)
      __hip_atomic_store(&p.ct[vid], (unsigned)(2 * layer + 3),
                         __ATOMIC_RELAXED, __HIP_MEMORY_SCOPE_AGENT);
    // spin: siblings (z slices) + neighbor strips (halo), ct >= 2*layer+3
    if (wv == 0 && lane < 11) {
      int idx = -1;
      if (lane < 3) idx = g * 4 + ((y + 1 + lane) & 3);
      else {
        int k = lane - 3;
        int xn2 = xt + ((k >> 2) ? step : -step);
        if (xn2 >= 0 && xn2 <= 12) idx = (n * 13 + xn2) * 4 + (k & 3);
      }
      if (idx >= 0) {
        unsigned tgt = (unsigned)(2 * layer + 3);
        while (__hip_atomic_load(&p.ct[idx], __ATOMIC_RELAXED, __HIP_MEMORY_SCOPE_AGENT) < tgt)
          __builtin_amdgcn_s_sleep(1);
      }
    }
    __syncthreads();
    // ===== sibling z slices -> Zs (normal cached loads) =====
    {
      int col = tid >> 3, k8 = tid & 7;
#pragma unroll
      for (int s = 1; s < 4; ++s) {
        int sd0g = ((y + s) & 3) * 16;    // dgrp base of sibling slice
#pragma unroll
        for (int q = 0; q < 2; ++q) {
          int dg = sd0g + k8 * 2 + q;
          bf16x8 zv = *(const bf16x8*)(zstrip + (size_t)col * 512 + dg * 8);
          *(bf16x8*)(ZsRaw + dg * SG + col * 16) = zv;
        }
      }
    }
    __syncthreads();

    // ===== B3 = BN3(dconv(z)) -> Bs ; wave: 8 rows, lane owns 8 d =====
    {
      const float* wdp = p.wd + (size_t)layer * D_ * 3 + lane * 24;
      float4 wq[6];
#pragma unroll
      for (int q = 0; q < 6; ++q) wq[q] = *(const float4*)(wdp + 4 * q);
      float4 s3a = *(const float4*)(s3p + lane * 8), s3b = *(const float4*)(s3p + lane * 8 + 4);
      float4 o3a = *(const float4*)(o3p + lane * 8), o3b = *(const float4*)(o3p + lane * 8 + 4);
      const unsigned short* zlay = p.zg + (size_t)layer * ZB;
#pragma unroll
      for (int rr = 0; rr < 8; ++rr) {
        int row = wv * 8 + rr;
        int gcol = l0 + row;
        bf16x8 zc = *(bf16x8*)(ZsRaw + lane * SG + row * 16);
        bf16x8 zl = {0, 0, 0, 0, 0, 0, 0, 0};
        bf16x8 zr = {0, 0, 0, 0, 0, 0, 0, 0};
        int gl2 = gcol - dil, gr2 = gcol + dil;
        if (gl2 >= 0) {
          if (gl2 >= l0) zl = *(bf16x8*)(ZsRaw + lane * SG + (gl2 - l0) * 16);
          else zl = *(const bf16x8*)(zlay + (size_t)(n * 13 + (gl2 >> 6)) * (64 * 512)
                                     + (size_t)(gl2 & 63) * 512 + lane * 8);
        }
        if (gr2 < L_) {
          if (gr2 < l0 + 64) zr = *(bf16x8*)(ZsRaw + lane * SG + (gr2 - l0) * 16);
          else zr = *(const bf16x8*)(zlay + (size_t)(n * 13 + (gr2 >> 6)) * (64 * 512)
                                     + (size_t)(gr2 & 63) * 512 + lane * 8);
        }
        bf16x8 pb;
#pragma unroll
        for (int j = 0; j < 8; ++j) {
          float w0 = wq[(3 * j + 0) >> 2][(3 * j + 0) & 3];
          float w1v = wq[(3 * j + 1) >> 2][(3 * j + 1) & 3];
          float w2v = wq[(3 * j + 2) >> 2][(3 * j + 2) & 3];
          float m = bf2f(zc[j]) * w1v;
          m = fmaf(bf2f(zl[j]), w0, m);
          m = fmaf(bf2f(zr[j]), w2v, m);
          float s3v = (j < 4) ? s3a[j] : s3b[j - 4];
          float o3v = (j < 4) ? o3a[j] : o3b[j - 4];
          pb[j] = f2bf(fmaf(m, s3v, o3v));
        }
        *(bf16x8*)(BsRaw + lane * SG + row * 16) = pb;
      }
    }
    __syncthreads();

    // ===== stage2 MFMA: c-slice [y*64,+64) x cols 64, K=512 ; hreg += =====
    {
      f32x4 acc2[2] = {};
      const short* W2 = p.w2b + (size_t)layer * C_ * D_ + (size_t)(y * 64 + cw * 16 + frow) * D_;
#pragma unroll
      for (int k0 = 0; k0 < 16; ++k0) {
        int kb = k0 * 32 + kg * 8;
        bf16x8 af = *(const bf16x8*)(W2 + kb);
#pragma unroll
        for (int jb = 0; jb < 2; ++jb) {
          int col = ch * 32 + jb * 16 + frow;
          bf16x8 bfr = *(bf16x8*)(BsRaw + (k0 * 4 + kg) * SG + col * 16);
          acc2[jb] = __builtin_amdgcn_mfma_f32_16x16x32_bf16(af, bfr, acc2[jb], 0, 0, 0);
        }
      }
#pragma unroll
      for (int jb = 0; jb < 2; ++jb)
#pragma unroll
        for (int jj = 0; jj < 4; ++jj)
          hreg[jb][jj] += acc2[jb][jj];
    }
    // publish h' (own c-slice) for next layer's B1
#pragma unroll
    for (int jb = 0; jb < 2; ++jb) {
      int gl = l0 + ch * 32 + jb * 16 + frow;
      if (gl < L_) {
        float tmp[4] = {hreg[jb][0], hreg[jb][1], hreg[jb][2], hreg[jb][3]};
        u64 u0, u1;
        __builtin_memcpy(&u0, &tmp[0], 8);
        __builtin_memcpy(&u1, &tmp[2], 8);
        float* dst = hb_nxt + (size_t)gl * C_ + cbase;
        astore8(dst, u0);
        astore8(dst + 2, u1);
      }
    }
    __syncthreads();
    if (tid == 0)
      __hip_atomic_store(&p.ct[vid], (unsigned)(2 * layer + 4),
                         __ATOMIC_RELAXED, __HIP_MEMORY_SCOPE_AGENT);
  }

  // ---------------- mask: y = xe * sigmoid(h) -> yb (own fragment) ----------
  {
    float* yn = p.yb + (size_t)n * ((size_t)L_ * C_);
#pragma unroll
    for (int jb = 0; jb < 2; ++jb) {
      int gl = l0 + ch * 32 + jb * 16 + frow;
      if (gl < L_) {
        float4 v;
        v.x = xer[jb][0] / (1.f + expf(-hreg[jb][0]));
        v.y = xer[jb][1] / (1.f + expf(-hreg[jb][1]));
        v.z = xer[jb][2] / (1.f + expf(-hreg[jb][2]));
        v.w = xer[jb][3] / (1.f + expf(-hreg[jb][3]));
        *(float4*)(yn + (size_t)gl * C_ + cbase) = v;
      }
    }
  }
  bar_heavy(p.gbar, NVALID, tid);

  // ---------------- decoder (indexed by logical id over 208 blocks) --------
  for (int idx = vid * NTHR + tid; idx < NBATCH * T_; idx += NVALID * NTHR) {
    int t = idx % T_;
    int nn = idx / T_;
    int tt = t + FK_;
    int lq = tt / 10;      // in [2, 801]
    int k0 = tt % 10;
    const float* y0 = p.yb + (size_t)nn * ((size_t)L_ * C_) + (size_t)lq * C_;
    const float* y1 = y0 - C_;
    float acc = 0.f;
#pragma unroll 8
    for (int c = 0; c < C_; c++) {
      const float* wr2 = p.w_dec + c * FK_;
      acc = fmaf(y0[c], wr2[k0], acc);
      acc = fmaf(y1[c], wr2[k0 + 10], acc);
    }
    p.out[idx] = acc;
  }
}

extern "C" void kernel_launch(void* const* d_in, const int* in_sizes, int n_in,
                              void* d_out, int out_size, void* d_ws, size_t ws_size,
                              hipStream_t stream) {
  KParams hp;
  hp.x     = (const float*)d_in[0];
  hp.w_enc = (const float*)d_in[1];
  hp.w1    = (const float*)d_in[2];
  hp.wd    = (const float*)d_in[3];
  hp.w2    = (const float*)d_in[4];
  hp.w_dec = (const float*)d_in[5];
  hp.g1 = (const float*)d_in[6];  hp.bb1 = (const float*)d_in[7];
  hp.m1 = (const float*)d_in[8];  hp.v1  = (const float*)d_in[9];
  hp.g2 = (const float*)d_in[10]; hp.bb2 = (const float*)d_in[11];
  hp.m2 = (const float*)d_in[12]; hp.v2  = (const float*)d_in[13];
  hp.g3 = (const float*)d_in[14]; hp.bb3 = (const float*)d_in[15];
  hp.m3 = (const float*)d_in[16]; hp.v3  = (const float*)d_in[17];
  hp.out = (float*)d_out;

  char* cur = (char*)d_ws;
  auto take = [&](size_t bytes) { char* r = cur; cur += (bytes + 255) & ~(size_t)255; return r; };
  hp.gbar = (Bar*)take(256);
  hp.ct   = (unsigned*)take(NVALID * 4);
  hp.s1 = (float*)take(NB_ * C_ * 4);
  hp.o1 = (float*)take(NB_ * C_ * 4);
  hp.s2 = (float*)take(NB_ * D_ * 4);
  hp.o2 = (float*)take(NB_ * D_ * 4);
  hp.s3 = (float*)take(NB_ * D_ * 4);
  hp.o3 = (float*)take(NB_ * D_ * 4);
  hp.yb  = (float*)take((size_t)NBATCH * L_ * C_ * 4);
  hp.w1b = (short*)take((size_t)NB_ * D_ * C_ * 2);
  hp.w2b = (short*)take((size_t)NB_ * D_ * C_ * 2);
  hp.hb  = (float*)take((size_t)(NB_ + 1) * NBATCH * L_ * C_ * 4);   // 33 bufs
  hp.zg  = (unsigned short*)take((size_t)NB_ * 52 * 64 * 512 * 2);   // 32 bufs

  hipMemsetAsync(d_ws, 0, 2048, stream);   // gbar + ct
  prep_kernel<<<dim3(1024), dim3(256), 0, stream>>>(hp);
  tasnet_fused<<<dim3(NGRID), dim3(NTHR), 0, stream>>>(hp);
}

// Round 18
// 555.954 us; speedup vs baseline: 1.7001x; 1.1272x over previous
//
#include <hip/hip_runtime.h>
#include <cstddef>
#include <cstring>

#define T_     8000
#define L_     803
#define C_     256
#define D_     512
#define NB_    32
#define FK_    20
#define NBATCH 4
#define EPS_   1e-5f

#define NVALID 208           // 52 strips x 4 slices (logical blocks)
#define NGRID  224           // physical grid; g>=52 exits early
#define NTHR   512           // 8 waves
#define SG     1040          // LDS group stride bytes: 64 cols * 16B + 16B pad

typedef __attribute__((ext_vector_type(8))) short bf16x8;
typedef __attribute__((ext_vector_type(4))) short shortx4;
typedef __attribute__((ext_vector_type(4))) float f32x4;
typedef unsigned long long u64;

__device__ __forceinline__ short f2bf(float x) {
  unsigned u = __float_as_uint(x);
  u += 0x7FFF + ((u >> 16) & 1);   // RNE
  return (short)(u >> 16);
}
__device__ __forceinline__ float bf2f(short u) {
  return __uint_as_float(((unsigned)(unsigned short)u) << 16);
}

__device__ __forceinline__ void astore8(void* p, u64 v) {
  __hip_atomic_store((u64*)p, v, __ATOMIC_RELAXED, __HIP_MEMORY_SCOPE_AGENT);
}

struct __align__(64) Bar { unsigned cnt; unsigned phase; unsigned pad[14]; };

__device__ __forceinline__ void bar_heavy(Bar* b, unsigned nblk, int tid) {
  __syncthreads();
  if (tid == 0) {
    __threadfence();
    unsigned ph = __hip_atomic_load(&b->phase, __ATOMIC_RELAXED, __HIP_MEMORY_SCOPE_AGENT);
    unsigned prev = __hip_atomic_fetch_add(&b->cnt, 1u, __ATOMIC_RELAXED, __HIP_MEMORY_SCOPE_AGENT);
    if (prev == nblk - 1) {
      __hip_atomic_store(&b->cnt, 0u, __ATOMIC_RELAXED, __HIP_MEMORY_SCOPE_AGENT);
      __hip_atomic_store(&b->phase, ph + 1u, __ATOMIC_RELEASE, __HIP_MEMORY_SCOPE_AGENT);
    } else {
      while (__hip_atomic_load(&b->phase, __ATOMIC_RELAXED, __HIP_MEMORY_SCOPE_AGENT) == ph)
        __builtin_amdgcn_s_sleep(2);
    }
    __threadfence();
  }
  __syncthreads();
}

struct KParams {
  const float *x, *w_enc, *w1, *wd, *w2, *w_dec;
  const float *g1, *bb1, *m1, *v1;
  const float *g2, *bb2, *m2, *v2;
  const float *g3, *bb3, *m3, *v3;
  float *out;
  float *s1, *o1, *s2, *o2, *s3, *o3;
  float *yb;                  // y [n][l][c] f32
  short *w1b, *w2b;           // bf16 weights
  unsigned short *zg;         // z: [32 buf][52 strip][64 col][512 d] bf16
  unsigned short *b1b;        // BN1(h) staged: [32 buf][n][l][c] bf16
  unsigned *ct;               // per-logical-block monotone counter [208]
  Bar *gbar;
};

// ---------- full-grid prep: BN fold + weight bf16 conversion ----------
__global__ __launch_bounds__(256) void prep_kernel(KParams p) {
  const int gtid = blockIdx.x * 256 + threadIdx.x;
  const int stride = gridDim.x * 256;
  for (int i = gtid; i < NB_ * C_; i += stride) {
    float s = p.g1[i] * rsqrtf(p.v1[i] + EPS_);
    p.s1[i] = s; p.o1[i] = p.bb1[i] - p.m1[i] * s;
  }
  for (int i = gtid; i < NB_ * D_; i += stride) {
    float s2 = p.g2[i] * rsqrtf(p.v2[i] + EPS_);
    p.s2[i] = s2; p.o2[i] = p.bb2[i] - p.m2[i] * s2;
    float s3 = p.g3[i] * rsqrtf(p.v3[i] + EPS_);
    p.s3[i] = s3; p.o3[i] = p.bb3[i] - p.m3[i] * s3;
  }
  for (int i = gtid; i < NB_ * D_ * C_ / 4; i += stride) {
    float4 a = ((const float4*)p.w1)[i];
    float4 b = ((const float4*)p.w2)[i];
    shortx4 sa, sb;
    sa[0] = f2bf(a.x); sa[1] = f2bf(a.y); sa[2] = f2bf(a.z); sa[3] = f2bf(a.w);
    sb[0] = f2bf(b.x); sb[1] = f2bf(b.y); sb[2] = f2bf(b.z); sb[3] = f2bf(b.w);
    *(shortx4*)&p.w1b[4 * i] = sa;
    *(shortx4*)&p.w2b[4 * i] = sb;
  }
}

__global__ __launch_bounds__(NTHR) void tasnet_fused(KParams p) {
  const int tid = threadIdx.x;
  const int bid = blockIdx.x;

  // XCD swizzle: siblings (same strip, y=0..3) share bid%8 -> same XCD L2.
  const int r8 = bid & 7, t8 = bid >> 3;
  const int g = (t8 >> 2) * 8 + r8;           // strip-group 0..55
  const int y = t8 & 3;                       // slice
  if (g >= 52) return;                        // 16 surplus blocks exit
  const int vid = g * 4 + y;                  // logical block id 0..207
  const int xt = g % 13, n = g / 13;
  const int l0 = xt * 64;

  const int lane = tid & 63, wv = tid >> 6;   // 8 waves
  const int frow = lane & 15, kg = lane >> 4;
  const int cw = wv & 3;                      // c-subgroup  (stage2/hreg)
  const int ch = wv >> 2;                     // col-half    (stage2/hreg)
  const int cbase = y * 64 + cw * 16 + kg * 4;

  __shared__ __align__(16) char BsRaw[64 * SG];   // 66.5 KB  [kgrp][col][16B]
  __shared__ __align__(16) char ZsRaw[64 * SG];   // 66.5 KB  [dgrp][col][16B]

  const size_t B1B = (size_t)NBATCH * L_ * C_;    // shorts per b1 buffer
  const size_t ZB = (size_t)52 * 64 * 512;        // shorts per z buffer

  // ---------------- encoder -> hreg ; publish b1[0] = BN1_0(h0) -------------
  f32x4 hreg[2], xer[2];
  {
    const float* xn_ = p.x + (size_t)n * T_;
#pragma unroll
    for (int jb = 0; jb < 2; ++jb) {
      int gl = l0 + ch * 32 + jb * 16 + frow;
      int t0 = gl * 10 - 20;
      float xw[FK_];
#pragma unroll
      for (int k = 0; k < FK_; ++k) {
        int t = t0 + k;
        xw[k] = (t >= 0 && t < T_) ? xn_[t] : 0.f;
      }
#pragma unroll
      for (int jj = 0; jj < 4; ++jj) {
        const float* w = p.w_enc + (cbase + jj) * FK_;
        float acc = 0.f;
#pragma unroll
        for (int k = 0; k < FK_; ++k) acc = fmaf(xw[k], w[k], acc);
        hreg[jb][jj] = acc;
        xer[jb][jj] = acc;
      }
    }
    unsigned short* b0 = p.b1b + (size_t)n * (L_ * C_);
    float4 s1v = *(const float4*)(p.s1 + cbase);
    float4 o1v = *(const float4*)(p.o1 + cbase);
#pragma unroll
    for (int jb = 0; jb < 2; ++jb) {
      int gl = l0 + ch * 32 + jb * 16 + frow;
      if (gl < L_) {
        shortx4 pk;
        pk[0] = f2bf(fmaf(hreg[jb][0], s1v.x, o1v.x));
        pk[1] = f2bf(fmaf(hreg[jb][1], s1v.y, o1v.y));
        pk[2] = f2bf(fmaf(hreg[jb][2], s1v.z, o1v.z));
        pk[3] = f2bf(fmaf(hreg[jb][3], s1v.w, o1v.w));
        *(shortx4*)(b0 + (size_t)gl * C_ + cbase) = pk;   // normal: same-XCD readers
      }
    }
  }
  __syncthreads();
  if (tid == 0)
    __hip_atomic_store(&p.ct[vid], 2u, __ATOMIC_RELAXED, __HIP_MEMORY_SCOPE_AGENT);

  // ---------------- 32 residual blocks ----------------
  for (int layer = 0; layer < NB_; ++layer) {
    const int dil = 1 << (layer & 7);
    const int step = (dil <= 64) ? 1 : 2;
    const float* s1p = p.s1 + layer * C_;
    const float* o1p = p.o1 + layer * C_;
    const float* s2p = p.s2 + layer * D_;
    const float* o2p = p.o2 + layer * D_;
    const float* s3p = p.s3 + layer * D_;
    const float* o3p = p.o3 + layer * D_;
    const unsigned short* b1_cur = p.b1b + (size_t)layer * B1B + (size_t)n * (L_ * C_);
    unsigned short* b1_nxt = p.b1b + (size_t)(layer + 1) * B1B + (size_t)n * (L_ * C_);
    unsigned short* zstrip = p.zg + (size_t)layer * ZB + (size_t)(n * 13 + xt) * (64 * 512);

    // ===== B1 own slice: BN1(hreg) -> Bs =====
    {
      float4 s1v = *(const float4*)(s1p + cbase);
      float4 o1v = *(const float4*)(o1p + cbase);
#pragma unroll
      for (int jb = 0; jb < 2; ++jb) {
        int col = ch * 32 + jb * 16 + frow;
        shortx4 pk;
        pk[0] = f2bf(fmaf(hreg[jb][0], s1v.x, o1v.x));
        pk[1] = f2bf(fmaf(hreg[jb][1], s1v.y, o1v.y));
        pk[2] = f2bf(fmaf(hreg[jb][2], s1v.z, o1v.z));
        pk[3] = f2bf(fmaf(hreg[jb][3], s1v.w, o1v.w));
        *(shortx4*)(BsRaw + (cbase >> 3) * SG + col * 16 + (kg & 1) * 8) = pk;
      }
    }
    // spin: siblings' b1(layer) published (ct >= 2+2*layer)
    if (wv == 0 && lane < 3) {
      int idx = g * 4 + ((y + 1 + lane) & 3);
      unsigned tgt = 2u + 2u * (unsigned)layer;
      while (__hip_atomic_load(&p.ct[idx], __ATOMIC_RELAXED, __HIP_MEMORY_SCOPE_AGENT) < tgt)
        __builtin_amdgcn_s_sleep(1);
    }
    __syncthreads();
    // ===== B1 sibling slices: pure bf16 copy b1b -> Bs (L2 hits) =====
    {
      int col = tid >> 3, k8 = tid & 7;
      int gl = l0 + col;
      bool lv = gl < L_;
#pragma unroll
      for (int s = 1; s < 4; ++s) {
        int sc = ((y + s) & 3) * 64 + k8 * 8;
        bf16x8 pk = {0, 0, 0, 0, 0, 0, 0, 0};
        if (lv) pk = *(const bf16x8*)(b1_cur + (size_t)gl * C_ + sc);
        *(bf16x8*)(BsRaw + (sc >> 3) * SG + col * 16) = pk;
      }
    }
    __syncthreads();

    // ===== stage1 MFMA: d-slice [y*128,+128) x cols 64, K=256 =====
    f32x4 acc1[4] = {};
    {
      const short* W1 = p.w1b + (size_t)layer * D_ * C_ + (size_t)(y * 128 + wv * 16 + frow) * C_;
#pragma unroll
      for (int k0 = 0; k0 < 8; ++k0) {
        int kb = k0 * 32 + kg * 8;
        bf16x8 af = *(const bf16x8*)(W1 + kb);
#pragma unroll
        for (int jb = 0; jb < 4; ++jb) {
          bf16x8 bfr = *(bf16x8*)(BsRaw + (k0 * 4 + kg) * SG + (jb * 16 + frow) * 16);
          acc1[jb] = __builtin_amdgcn_mfma_f32_16x16x32_bf16(af, bfr, acc1[jb], 0, 0, 0);
        }
      }
    }
    // ===== z = BN2(acc1) -> Zs + publish (normal; sc1 only for cross-XCD halo)
    {
      const int w = (dil < 64) ? dil : 64;
      const int rdL = xt - step, rdR = xt + step;
      const bool pubL = (rdL >= 0);
      const bool pubR = (rdR <= 12);
      int db = y * 128 + wv * 16 + kg * 4;
      float4 s2v = *(const float4*)(s2p + db);
      float4 o2v = *(const float4*)(o2p + db);
#pragma unroll
      for (int jb = 0; jb < 4; ++jb) {
        int col = jb * 16 + frow;
        shortx4 pk;
        pk[0] = f2bf(fmaf(acc1[jb][0], s2v.x, o2v.x));
        pk[1] = f2bf(fmaf(acc1[jb][1], s2v.y, o2v.y));
        pk[2] = f2bf(fmaf(acc1[jb][2], s2v.z, o2v.z));
        pk[3] = f2bf(fmaf(acc1[jb][3], s2v.w, o2v.w));
        *(shortx4*)(ZsRaw + (db >> 3) * SG + col * 16 + (kg & 1) * 8) = pk;
        unsigned short* dst = zstrip + (size_t)col * 512 + db;
        bool haloL = pubL && (col < w);
        bool haloR = pubR && (col >= 64 - w);
        if (haloL || haloR) {
          u64 u;
          __builtin_memcpy(&u, &pk, 8);
          astore8(dst, u);                 // cross-XCD reader: via IF$
        } else {
          *(shortx4*)dst = pk;             // same-XCD siblings: via shared L2
        }
      }
    }
    __syncthreads();
    if (tid == 0)
      __hip_atomic_store(&p.ct[vid], (unsigned)(2 * layer + 3),
                         __ATOMIC_RELAXED, __HIP_MEMORY_SCOPE_AGENT);
    // spin: siblings (z slices) + neighbor strips (halo), ct >= 2*layer+3
    if (wv == 0 && lane < 11) {
      int idx = -1;
      if (lane < 3) idx = g * 4 + ((y + 1 + lane) & 3);
      else {
        int k = lane - 3;
        int xn2 = xt + ((k >> 2) ? step : -step);
        if (xn2 >= 0 && xn2 <= 12) idx = (n * 13 + xn2) * 4 + (k & 3);
      }
      if (idx >= 0) {
        unsigned tgt = (unsigned)(2 * layer + 3);
        while (__hip_atomic_load(&p.ct[idx], __ATOMIC_RELAXED, __HIP_MEMORY_SCOPE_AGENT) < tgt)
          __builtin_amdgcn_s_sleep(1);
      }
    }
    __syncthreads();
    // ===== sibling z slices -> Zs (normal cached loads, L2 hits) =====
    {
      int col = tid >> 3, k8 = tid & 7;
#pragma unroll
      for (int s = 1; s < 4; ++s) {
        int sd0g = ((y + s) & 3) * 16;    // dgrp base of sibling slice
#pragma unroll
        for (int q = 0; q < 2; ++q) {
          int dg = sd0g + k8 * 2 + q;
          bf16x8 zv = *(const bf16x8*)(zstrip + (size_t)col * 512 + dg * 8);
          *(bf16x8*)(ZsRaw + dg * SG + col * 16) = zv;
        }
      }
    }
    __syncthreads();

    // ===== B3 = BN3(dconv(z)) -> Bs ; wave: 8 rows, lane owns 8 d =====
    {
      const float* wdp = p.wd + (size_t)layer * D_ * 3 + lane * 24;
      float4 wq[6];
#pragma unroll
      for (int q = 0; q < 6; ++q) wq[q] = *(const float4*)(wdp + 4 * q);
      float4 s3a = *(const float4*)(s3p + lane * 8), s3b = *(const float4*)(s3p + lane * 8 + 4);
      float4 o3a = *(const float4*)(o3p + lane * 8), o3b = *(const float4*)(o3p + lane * 8 + 4);
      const unsigned short* zlay = p.zg + (size_t)layer * ZB;
#pragma unroll
      for (int rr = 0; rr < 8; ++rr) {
        int row = wv * 8 + rr;
        int gcol = l0 + row;
        bf16x8 zc = *(bf16x8*)(ZsRaw + lane * SG + row * 16);
        bf16x8 zl = {0, 0, 0, 0, 0, 0, 0, 0};
        bf16x8 zr = {0, 0, 0, 0, 0, 0, 0, 0};
        int gl2 = gcol - dil, gr2 = gcol + dil;
        if (gl2 >= 0) {
          if (gl2 >= l0) zl = *(bf16x8*)(ZsRaw + lane * SG + (gl2 - l0) * 16);
          else zl = *(const bf16x8*)(zlay + (size_t)(n * 13 + (gl2 >> 6)) * (64 * 512)
                                     + (size_t)(gl2 & 63) * 512 + lane * 8);
        }
        if (gr2 < L_) {
          if (gr2 < l0 + 64) zr = *(bf16x8*)(ZsRaw + lane * SG + (gr2 - l0) * 16);
          else zr = *(const bf16x8*)(zlay + (size_t)(n * 13 + (gr2 >> 6)) * (64 * 512)
                                     + (size_t)(gr2 & 63) * 512 + lane * 8);
        }
        bf16x8 pb;
#pragma unroll
        for (int j = 0; j < 8; ++j) {
          float w0 = wq[(3 * j + 0) >> 2][(3 * j + 0) & 3];
          float w1v = wq[(3 * j + 1) >> 2][(3 * j + 1) & 3];
          float w2v = wq[(3 * j + 2) >> 2][(3 * j + 2) & 3];
          float m = bf2f(zc[j]) * w1v;
          m = fmaf(bf2f(zl[j]), w0, m);
          m = fmaf(bf2f(zr[j]), w2v, m);
          float s3v = (j < 4) ? s3a[j] : s3b[j - 4];
          float o3v = (j < 4) ? o3a[j] : o3b[j - 4];
          pb[j] = f2bf(fmaf(m, s3v, o3v));
        }
        *(bf16x8*)(BsRaw + lane * SG + row * 16) = pb;
      }
    }
    __syncthreads();

    // ===== stage2 MFMA: c-slice [y*64,+64) x cols 64, K=512 ; hreg += =====
    {
      f32x4 acc2[2] = {};
      const short* W2 = p.w2b + (size_t)layer * C_ * D_ + (size_t)(y * 64 + cw * 16 + frow) * D_;
#pragma unroll
      for (int k0 = 0; k0 < 16; ++k0) {
        int kb = k0 * 32 + kg * 8;
        bf16x8 af = *(const bf16x8*)(W2 + kb);
#pragma unroll
        for (int jb = 0; jb < 2; ++jb) {
          int col = ch * 32 + jb * 16 + frow;
          bf16x8 bfr = *(bf16x8*)(BsRaw + (k0 * 4 + kg) * SG + col * 16);
          acc2[jb] = __builtin_amdgcn_mfma_f32_16x16x32_bf16(af, bfr, acc2[jb], 0, 0, 0);
        }
      }
#pragma unroll
      for (int jb = 0; jb < 2; ++jb)
#pragma unroll
        for (int jj = 0; jj < 4; ++jj)
          hreg[jb][jj] += acc2[jb][jj];
    }
    // publish b1[layer+1] = BN1_{l+1}(h') (normal stores; siblings same XCD)
    if (layer + 1 < NB_) {
      float4 s1v = *(const float4*)(p.s1 + (layer + 1) * C_ + cbase);
      float4 o1v = *(const float4*)(p.o1 + (layer + 1) * C_ + cbase);
#pragma unroll
      for (int jb = 0; jb < 2; ++jb) {
        int gl = l0 + ch * 32 + jb * 16 + frow;
        if (gl < L_) {
          shortx4 pk;
          pk[0] = f2bf(fmaf(hreg[jb][0], s1v.x, o1v.x));
          pk[1] = f2bf(fmaf(hreg[jb][1], s1v.y, o1v.y));
          pk[2] = f2bf(fmaf(hreg[jb][2], s1v.z, o1v.z));
          pk[3] = f2bf(fmaf(hreg[jb][3], s1v.w, o1v.w));
          *(shortx4*)(b1_nxt + (size_t)gl * C_ + cbase) = pk;
        }
      }
    }
    __syncthreads();
    if (tid == 0)
      __hip_atomic_store(&p.ct[vid], (unsigned)(2 * layer + 4),
                         __ATOMIC_RELAXED, __HIP_MEMORY_SCOPE_AGENT);
  }

  // ---------------- mask: y = xe * sigmoid(h) -> yb (own fragment) ----------
  {
    float* yn = p.yb + (size_t)n * ((size_t)L_ * C_);
#pragma unroll
    for (int jb = 0; jb < 2; ++jb) {
      int gl = l0 + ch * 32 + jb * 16 + frow;
      if (gl < L_) {
        float4 v;
        v.x = xer[jb][0] / (1.f + expf(-hreg[jb][0]));
        v.y = xer[jb][1] / (1.f + expf(-hreg[jb][1]));
        v.z = xer[jb][2] / (1.f + expf(-hreg[jb][2]));
        v.w = xer[jb][3] / (1.f + expf(-hreg[jb][3]));
        *(float4*)(yn + (size_t)gl * C_ + cbase) = v;   // bar_heavy publishes
      }
    }
  }
  bar_heavy(p.gbar, NVALID, tid);

  // ---------------- decoder (indexed by logical id over 208 blocks) --------
  for (int idx = vid * NTHR + tid; idx < NBATCH * T_; idx += NVALID * NTHR) {
    int t = idx % T_;
    int nn = idx / T_;
    int tt = t + FK_;
    int lq = tt / 10;      // in [2, 801]
    int k0 = tt % 10;
    const float* y0 = p.yb + (size_t)nn * ((size_t)L_ * C_) + (size_t)lq * C_;
    const float* y1 = y0 - C_;
    float acc = 0.f;
#pragma unroll 8
    for (int c = 0; c < C_; c++) {
      const float* wr2 = p.w_dec + c * FK_;
      acc = fmaf(y0[c], wr2[k0], acc);
      acc = fmaf(y1[c], wr2[k0 + 10], acc);
    }
    p.out[idx] = acc;
  }
}

extern "C" void kernel_launch(void* const* d_in, const int* in_sizes, int n_in,
                              void* d_out, int out_size, void* d_ws, size_t ws_size,
                              hipStream_t stream) {
  KParams hp;
  hp.x     = (const float*)d_in[0];
  hp.w_enc = (const float*)d_in[1];
  hp.w1    = (const float*)d_in[2];
  hp.wd    = (const float*)d_in[3];
  hp.w2    = (const float*)d_in[4];
  hp.w_dec = (const float*)d_in[5];
  hp.g1 = (const float*)d_in[6];  hp.bb1 = (const float*)d_in[7];
  hp.m1 = (const float*)d_in[8];  hp.v1  = (const float*)d_in[9];
  hp.g2 = (const float*)d_in[10]; hp.bb2 = (const float*)d_in[11];
  hp.m2 = (const float*)d_in[12]; hp.v2  = (const float*)d_in[13];
  hp.g3 = (const float*)d_in[14]; hp.bb3 = (const float*)d_in[15];
  hp.m3 = (const float*)d_in[16]; hp.v3  = (const float*)d_in[17];
  hp.out = (float*)d_out;

  char* cur = (char*)d_ws;
  auto take = [&](size_t bytes) { char* r = cur; cur += (bytes + 255) & ~(size_t)255; return r; };
  hp.gbar = (Bar*)take(256);
  hp.ct   = (unsigned*)take(NVALID * 4);
  hp.s1 = (float*)take(NB_ * C_ * 4);
  hp.o1 = (float*)take(NB_ * C_ * 4);
  hp.s2 = (float*)take(NB_ * D_ * 4);
  hp.o2 = (float*)take(NB_ * D_ * 4);
  hp.s3 = (float*)take(NB_ * D_ * 4);
  hp.o3 = (float*)take(NB_ * D_ * 4);
  hp.yb  = (float*)take((size_t)NBATCH * L_ * C_ * 4);
  hp.w1b = (short*)take((size_t)NB_ * D_ * C_ * 2);
  hp.w2b = (short*)take((size_t)NB_ * D_ * C_ * 2);
  hp.b1b = (unsigned short*)take((size_t)NB_ * NBATCH * L_ * C_ * 2);  // 32 bufs
  hp.zg  = (unsigned short*)take((size_t)NB_ * 52 * 64 * 512 * 2);     // 32 bufs

  hipMemsetAsync(d_ws, 0, 2048, stream);   // gbar + ct
  prep_kernel<<<dim3(1024), dim3(256), 0, stream>>>(hp);
  tasnet_fused<<<dim3(NGRID), dim3(NTHR), 0, stream>>>(hp);
}

// Round 19
// 516.178 us; speedup vs baseline: 1.8311x; 1.0771x over previous
//
#include <hip/hip_runtime.h>
#include <cstddef>
#include <cstring>

#define T_     8000
#define L_     803
#define C_     256
#define D_     512
#define NB_    32
#define FK_    20
#define NBATCH 4
#define EPS_   1e-5f

#define NVALID 208           // 52 strips x 4 slices (logical blocks)
#define NGRID  224           // physical grid; g>=52 exits early
#define NTHR   512           // 8 waves
#define SG     1040          // LDS group stride bytes: 64 cols * 16B + 16B pad

typedef __attribute__((ext_vector_type(8))) short bf16x8;
typedef __attribute__((ext_vector_type(4))) short shortx4;
typedef __attribute__((ext_vector_type(4))) float f32x4;
typedef unsigned long long u64;

__device__ __forceinline__ short f2bf(float x) {
  unsigned u = __float_as_uint(x);
  u += 0x7FFF + ((u >> 16) & 1);   // RNE
  return (short)(u >> 16);
}
__device__ __forceinline__ float bf2f(short u) {
  return __uint_as_float(((unsigned)(unsigned short)u) << 16);
}

__device__ __forceinline__ void astore8(void* p, u64 v) {
  __hip_atomic_store((u64*)p, v, __ATOMIC_RELAXED, __HIP_MEMORY_SCOPE_AGENT);
}

struct __align__(64) Bar { unsigned cnt; unsigned phase; unsigned pad[14]; };

__device__ __forceinline__ void bar_heavy(Bar* b, unsigned nblk, int tid) {
  __syncthreads();
  if (tid == 0) {
    __threadfence();
    unsigned ph = __hip_atomic_load(&b->phase, __ATOMIC_RELAXED, __HIP_MEMORY_SCOPE_AGENT);
    unsigned prev = __hip_atomic_fetch_add(&b->cnt, 1u, __ATOMIC_RELAXED, __HIP_MEMORY_SCOPE_AGENT);
    if (prev == nblk - 1) {
      __hip_atomic_store(&b->cnt, 0u, __ATOMIC_RELAXED, __HIP_MEMORY_SCOPE_AGENT);
      __hip_atomic_store(&b->phase, ph + 1u, __ATOMIC_RELEASE, __HIP_MEMORY_SCOPE_AGENT);
    } else {
      while (__hip_atomic_load(&b->phase, __ATOMIC_RELAXED, __HIP_MEMORY_SCOPE_AGENT) == ph)
        __builtin_amdgcn_s_sleep(2);
    }
    __threadfence();
  }
  __syncthreads();
}

struct KParams {
  const float *x, *w_enc, *w1, *wd, *w2, *w_dec;
  const float *g1, *bb1, *m1, *v1;
  const float *g2, *bb2, *m2, *v2;
  const float *g3, *bb3, *m3, *v3;
  float *out;
  float *s1, *o1, *s2, *o2, *s3, *o3;
  float *yb;                  // y [n][l][c] f32
  short *w1b, *w2b;           // bf16 weights
  unsigned short *zh;         // z halo: [32][52 strip][4 y][64 col][128 d] bf16
  unsigned short *b3g;        // b3:     [16][52 strip][64 col][512 d] bf16
  unsigned short *b1b;        // BN1(h): [32][n][l][c] bf16
  unsigned *ct;               // per-logical-block monotone counter [208]
  Bar *gbar;
};

// ---------- full-grid prep: BN fold + weight bf16 conversion ----------
__global__ __launch_bounds__(256) void prep_kernel(KParams p) {
  const int gtid = blockIdx.x * 256 + threadIdx.x;
  const int stride = gridDim.x * 256;
  for (int i = gtid; i < NB_ * C_; i += stride) {
    float s = p.g1[i] * rsqrtf(p.v1[i] + EPS_);
    p.s1[i] = s; p.o1[i] = p.bb1[i] - p.m1[i] * s;
  }
  for (int i = gtid; i < NB_ * D_; i += stride) {
    float s2 = p.g2[i] * rsqrtf(p.v2[i] + EPS_);
    p.s2[i] = s2; p.o2[i] = p.bb2[i] - p.m2[i] * s2;
    float s3 = p.g3[i] * rsqrtf(p.v3[i] + EPS_);
    p.s3[i] = s3; p.o3[i] = p.bb3[i] - p.m3[i] * s3;
  }
  for (int i = gtid; i < NB_ * D_ * C_ / 4; i += stride) {
    float4 a = ((const float4*)p.w1)[i];
    float4 b = ((const float4*)p.w2)[i];
    shortx4 sa, sb;
    sa[0] = f2bf(a.x); sa[1] = f2bf(a.y); sa[2] = f2bf(a.z); sa[3] = f2bf(a.w);
    sb[0] = f2bf(b.x); sb[1] = f2bf(b.y); sb[2] = f2bf(b.z); sb[3] = f2bf(b.w);
    *(shortx4*)&p.w1b[4 * i] = sa;
    *(shortx4*)&p.w2b[4 * i] = sb;
  }
}

__global__ __launch_bounds__(NTHR) void tasnet_fused(KParams p) {
  const int tid = threadIdx.x;
  const int bid = blockIdx.x;

  // XCD swizzle: siblings (same strip, y=0..3) share bid%8 -> same XCD L2.
  const int r8 = bid & 7, t8 = bid >> 3;
  const int g = (t8 >> 2) * 8 + r8;           // strip-group 0..55
  const int y = t8 & 3;                       // slice
  if (g >= 52) return;
  const int vid = g * 4 + y;                  // logical block id
  const int xt = g % 13, n = g / 13;
  const int l0 = xt * 64;

  const int lane = tid & 63, wv = tid >> 6;   // 8 waves
  const int frow = lane & 15, kg = lane >> 4;
  const int cw = wv & 3;
  const int ch = wv >> 2;
  const int cbase = y * 64 + cw * 16 + kg * 4;

  __shared__ __align__(16) char BsRaw[64 * SG];   // 66.5 KB [kgrp 0..63][col][16B]
  __shared__ __align__(16) char ZsOwn[16 * SG];   // 16.6 KB [oct 0..15][col][16B] own z slice

  const size_t B1B = (size_t)NBATCH * L_ * C_;    // shorts per b1 buffer
  const size_t ZHB = (size_t)52 * 4 * 64 * 128;   // shorts per zh buffer
  const size_t B3B = (size_t)52 * 64 * 512;       // shorts per b3 buffer

  // ---------------- encoder -> hreg ; publish b1[0] ----------------
  f32x4 hreg[2], xer[2];
  {
    const float* xn_ = p.x + (size_t)n * T_;
#pragma unroll
    for (int jb = 0; jb < 2; ++jb) {
      int gl = l0 + ch * 32 + jb * 16 + frow;
      int t0 = gl * 10 - 20;
      float xw[FK_];
#pragma unroll
      for (int k = 0; k < FK_; ++k) {
        int t = t0 + k;
        xw[k] = (t >= 0 && t < T_) ? xn_[t] : 0.f;
      }
#pragma unroll
      for (int jj = 0; jj < 4; ++jj) {
        const float* w = p.w_enc + (cbase + jj) * FK_;
        float acc = 0.f;
#pragma unroll
        for (int k = 0; k < FK_; ++k) acc = fmaf(xw[k], w[k], acc);
        hreg[jb][jj] = acc;
        xer[jb][jj] = acc;
      }
    }
    unsigned short* b0 = p.b1b + (size_t)n * (L_ * C_);
    float4 s1v = *(const float4*)(p.s1 + cbase);
    float4 o1v = *(const float4*)(p.o1 + cbase);
#pragma unroll
    for (int jb = 0; jb < 2; ++jb) {
      int gl = l0 + ch * 32 + jb * 16 + frow;
      if (gl < L_) {
        shortx4 pk;
        pk[0] = f2bf(fmaf(hreg[jb][0], s1v.x, o1v.x));
        pk[1] = f2bf(fmaf(hreg[jb][1], s1v.y, o1v.y));
        pk[2] = f2bf(fmaf(hreg[jb][2], s1v.z, o1v.z));
        pk[3] = f2bf(fmaf(hreg[jb][3], s1v.w, o1v.w));
        *(shortx4*)(b0 + (size_t)gl * C_ + cbase) = pk;
      }
    }
  }
  __syncthreads();
  if (tid == 0)
    __hip_atomic_store(&p.ct[vid], 1u, __ATOMIC_RELAXED, __HIP_MEMORY_SCOPE_AGENT);

  // ---------------- 32 residual blocks ----------------
  for (int layer = 0; layer < NB_; ++layer) {
    const int dil = 1 << (layer & 7);
    const int step = (dil <= 64) ? 1 : 2;
    const int w = (dil < 64) ? dil : 64;
    const float* s1p = p.s1 + layer * C_;
    const float* o1p = p.o1 + layer * C_;
    const float* s2p = p.s2 + layer * D_;
    const float* o2p = p.o2 + layer * D_;
    const float* s3p = p.s3 + layer * D_;
    const float* o3p = p.o3 + layer * D_;
    const unsigned short* b1_cur = p.b1b + (size_t)layer * B1B + (size_t)n * (L_ * C_);
    unsigned short* b1_nxt = p.b1b + (size_t)(layer + 1) * B1B + (size_t)n * (L_ * C_);
    unsigned short* zh_my = p.zh + (size_t)layer * ZHB
                            + ((size_t)(n * 13 + xt) * 4 + y) * (64 * 128);
    unsigned short* b3s = p.b3g + (size_t)(layer & 15) * B3B
                          + (size_t)(n * 13 + xt) * (64 * 512);

    // ===== B1 own slice -> Bs =====
    {
      float4 s1v = *(const float4*)(s1p + cbase);
      float4 o1v = *(const float4*)(o1p + cbase);
#pragma unroll
      for (int jb = 0; jb < 2; ++jb) {
        int col = ch * 32 + jb * 16 + frow;
        shortx4 pk;
        pk[0] = f2bf(fmaf(hreg[jb][0], s1v.x, o1v.x));
        pk[1] = f2bf(fmaf(hreg[jb][1], s1v.y, o1v.y));
        pk[2] = f2bf(fmaf(hreg[jb][2], s1v.z, o1v.z));
        pk[3] = f2bf(fmaf(hreg[jb][3], s1v.w, o1v.w));
        *(shortx4*)(BsRaw + (cbase >> 3) * SG + col * 16 + (kg & 1) * 8) = pk;
      }
    }
    // S1: siblings' b1(layer) published (ct >= 3*layer+1)
    if (wv == 0 && lane < 3) {
      int idx = g * 4 + ((y + 1 + lane) & 3);
      unsigned tgt = (unsigned)(3 * layer + 1);
      while (__hip_atomic_load(&p.ct[idx], __ATOMIC_RELAXED, __HIP_MEMORY_SCOPE_AGENT) < tgt)
        __builtin_amdgcn_s_sleep(1);
    }
    __syncthreads();
    // sibling b1 slices -> Bs (cached)
    {
      int col = tid >> 3, k8 = tid & 7;
      int gl = l0 + col;
      bool lv = gl < L_;
#pragma unroll
      for (int s = 1; s < 4; ++s) {
        int sc = ((y + s) & 3) * 64 + k8 * 8;
        bf16x8 pk = {0, 0, 0, 0, 0, 0, 0, 0};
        if (lv) pk = *(const bf16x8*)(b1_cur + (size_t)gl * C_ + sc);
        *(bf16x8*)(BsRaw + (sc >> 3) * SG + col * 16) = pk;
      }
    }
    __syncthreads();

    // ===== stage1 MFMA: d-slice [y*128,+128) x 64 cols, K=256 =====
    f32x4 acc1[4] = {};
    {
      const short* W1 = p.w1b + (size_t)layer * D_ * C_ + (size_t)(y * 128 + wv * 16 + frow) * C_;
#pragma unroll
      for (int k0 = 0; k0 < 8; ++k0) {
        int kb = k0 * 32 + kg * 8;
        bf16x8 af = *(const bf16x8*)(W1 + kb);
#pragma unroll
        for (int jb = 0; jb < 4; ++jb) {
          bf16x8 bfr = *(bf16x8*)(BsRaw + (k0 * 4 + kg) * SG + (jb * 16 + frow) * 16);
          acc1[jb] = __builtin_amdgcn_mfma_f32_16x16x32_bf16(af, bfr, acc1[jb], 0, 0, 0);
        }
      }
    }
    // ===== z = BN2(acc1) -> ZsOwn + zh halo publish (sc1, cross-XCD) =====
    {
      const bool hasL = (xt - step) >= 0;
      const bool hasR = (xt + step) <= 12;
      int dbr = wv * 16 + kg * 4;                 // own-slice-relative d
      float4 s2v = *(const float4*)(s2p + y * 128 + dbr);
      float4 o2v = *(const float4*)(o2p + y * 128 + dbr);
#pragma unroll
      for (int jb = 0; jb < 4; ++jb) {
        int col = jb * 16 + frow;
        shortx4 pk;
        pk[0] = f2bf(fmaf(acc1[jb][0], s2v.x, o2v.x));
        pk[1] = f2bf(fmaf(acc1[jb][1], s2v.y, o2v.y));
        pk[2] = f2bf(fmaf(acc1[jb][2], s2v.z, o2v.z));
        pk[3] = f2bf(fmaf(acc1[jb][3], s2v.w, o2v.w));
        *(shortx4*)(ZsOwn + (dbr >> 3) * SG + col * 16 + (kg & 1) * 8) = pk;
        bool haloL = hasL && (col < w);
        bool haloR = hasR && (col >= 64 - w);
        if (haloL || haloR) {
          u64 u;
          __builtin_memcpy(&u, &pk, 8);
          astore8(zh_my + (size_t)col * 128 + dbr, u);
        }
      }
    }
    __syncthreads();   // ZsOwn ready; zh stores drained
    if (tid == 0)
      __hip_atomic_store(&p.ct[vid], (unsigned)(3 * layer + 2),
                         __ATOMIC_RELAXED, __HIP_MEMORY_SCOPE_AGENT);

    // ===== B3 own d-slice (two-pass: interior, then edges after S2) =====
    {
      const int col = tid >> 3;
      const int op = tid & 7;
      const int gcol = l0 + col;
      const int gl2 = gcol - dil, gr2 = gcol + dil;
      const bool remL = (gl2 >= 0) && (gl2 < l0);
      const bool remR = (gr2 < L_) && (gr2 >= l0 + 64);
      const bool isRem = remL || remR;
      const unsigned short* zhl = p.zh + (size_t)layer * ZHB;
#pragma unroll
      for (int pass = 0; pass < 2; ++pass) {
        if (pass == 1) {
          // S2: same-y neighbor strips' zh published (ct >= 3*layer+2)
          if (wv == 0 && lane < 2) {
            int xn2 = xt + ((lane == 0) ? -step : step);
            if (xn2 >= 0 && xn2 <= 12) {
              int idx = (n * 13 + xn2) * 4 + y;
              unsigned tgt = (unsigned)(3 * layer + 2);
              while (__hip_atomic_load(&p.ct[idx], __ATOMIC_RELAXED, __HIP_MEMORY_SCOPE_AGENT) < tgt)
                __builtin_amdgcn_s_sleep(1);
            }
          }
          __syncthreads();
        }
        if ((pass == 0) == isRem) continue;
#pragma unroll
        for (int oc = 0; oc < 2; ++oc) {
          int drel = op * 16 + oc * 8;
          int dglob = y * 128 + drel;
          const float* wdp = p.wd + (size_t)layer * D_ * 3 + dglob * 3;
          float4 wq[6];
#pragma unroll
          for (int q = 0; q < 6; ++q) wq[q] = *(const float4*)(wdp + 4 * q);
          float4 s3a = *(const float4*)(s3p + dglob), s3b = *(const float4*)(s3p + dglob + 4);
          float4 o3a = *(const float4*)(o3p + dglob), o3b = *(const float4*)(o3p + dglob + 4);
          bf16x8 zc = *(bf16x8*)(ZsOwn + (drel >> 3) * SG + col * 16);
          bf16x8 zl = {0, 0, 0, 0, 0, 0, 0, 0};
          bf16x8 zr = {0, 0, 0, 0, 0, 0, 0, 0};
          if (gl2 >= 0) {
            if (!remL) zl = *(bf16x8*)(ZsOwn + (drel >> 3) * SG + (gl2 - l0) * 16);
            else zl = *(const bf16x8*)(zhl + ((size_t)(n * 13 + (gl2 >> 6)) * 4 + y) * (64 * 128)
                                       + (size_t)(gl2 & 63) * 128 + drel);
          }
          if (gr2 < L_) {
            if (!remR) zr = *(bf16x8*)(ZsOwn + (drel >> 3) * SG + (gr2 - l0) * 16);
            else zr = *(const bf16x8*)(zhl + ((size_t)(n * 13 + (gr2 >> 6)) * 4 + y) * (64 * 128)
                                       + (size_t)(gr2 & 63) * 128 + drel);
          }
          bf16x8 pb;
#pragma unroll
          for (int j = 0; j < 8; ++j) {
            float w0v = wq[(3 * j + 0) >> 2][(3 * j + 0) & 3];
            float w1v = wq[(3 * j + 1) >> 2][(3 * j + 1) & 3];
            float w2v = wq[(3 * j + 2) >> 2][(3 * j + 2) & 3];
            float m = bf2f(zc[j]) * w1v;
            m = fmaf(bf2f(zl[j]), w0v, m);
            m = fmaf(bf2f(zr[j]), w2v, m);
            float s3v = (j < 4) ? s3a[j] : s3b[j - 4];
            float o3v = (j < 4) ? o3a[j] : o3b[j - 4];
            pb[j] = f2bf(fmaf(m, s3v, o3v));
          }
          *(bf16x8*)(BsRaw + (y * 16 + (drel >> 3)) * SG + col * 16) = pb;
          *(bf16x8*)(b3s + (size_t)col * 512 + dglob) = pb;   // normal: same-XCD siblings
        }
      }
    }
    __syncthreads();   // own b3 in Bs; b3g stores drained
    if (tid == 0)
      __hip_atomic_store(&p.ct[vid], (unsigned)(3 * layer + 3),
                         __ATOMIC_RELAXED, __HIP_MEMORY_SCOPE_AGENT);
    // S3: siblings' b3 published
    if (wv == 0 && lane < 3) {
      int idx = g * 4 + ((y + 1 + lane) & 3);
      unsigned tgt = (unsigned)(3 * layer + 3);
      while (__hip_atomic_load(&p.ct[idx], __ATOMIC_RELAXED, __HIP_MEMORY_SCOPE_AGENT) < tgt)
        __builtin_amdgcn_s_sleep(1);
    }
    __syncthreads();
    // sibling b3 -> Bs (cached)
    {
      int col = tid >> 3, k8 = tid & 7;
#pragma unroll
      for (int s = 1; s < 4; ++s) {
        int y2 = (y + s) & 3;
        const unsigned short* src = b3s + (size_t)col * 512 + y2 * 128 + k8 * 16;
        bf16x8 v0 = *(const bf16x8*)(src);
        bf16x8 v1 = *(const bf16x8*)(src + 8);
        *(bf16x8*)(BsRaw + (y2 * 16 + k8 * 2) * SG + col * 16) = v0;
        *(bf16x8*)(BsRaw + (y2 * 16 + k8 * 2 + 1) * SG + col * 16) = v1;
      }
    }
    __syncthreads();

    // ===== stage2 MFMA: c-slice [y*64,+64) x 64 cols, K=512 ; hreg += =====
    {
      f32x4 acc2[2] = {};
      const short* W2 = p.w2b + (size_t)layer * C_ * D_ + (size_t)(y * 64 + cw * 16 + frow) * D_;
#pragma unroll
      for (int k0 = 0; k0 < 16; ++k0) {
        int kb = k0 * 32 + kg * 8;
        bf16x8 af = *(const bf16x8*)(W2 + kb);
#pragma unroll
        for (int jb = 0; jb < 2; ++jb) {
          int col = ch * 32 + jb * 16 + frow;
          bf16x8 bfr = *(bf16x8*)(BsRaw + (k0 * 4 + kg) * SG + col * 16);
          acc2[jb] = __builtin_amdgcn_mfma_f32_16x16x32_bf16(af, bfr, acc2[jb], 0, 0, 0);
        }
      }
#pragma unroll
      for (int jb = 0; jb < 2; ++jb)
#pragma unroll
        for (int jj = 0; jj < 4; ++jj)
          hreg[jb][jj] += acc2[jb][jj];
    }
    // publish b1[layer+1] = BN1_{l+1}(h')
    if (layer + 1 < NB_) {
      float4 s1v = *(const float4*)(p.s1 + (layer + 1) * C_ + cbase);
      float4 o1v = *(const float4*)(p.o1 + (layer + 1) * C_ + cbase);
#pragma unroll
      for (int jb = 0; jb < 2; ++jb) {
        int gl = l0 + ch * 32 + jb * 16 + frow;
        if (gl < L_) {
          shortx4 pk;
          pk[0] = f2bf(fmaf(hreg[jb][0], s1v.x, o1v.x));
          pk[1] = f2bf(fmaf(hreg[jb][1], s1v.y, o1v.y));
          pk[2] = f2bf(fmaf(hreg[jb][2], s1v.z, o1v.z));
          pk[3] = f2bf(fmaf(hreg[jb][3], s1v.w, o1v.w));
          *(shortx4*)(b1_nxt + (size_t)gl * C_ + cbase) = pk;
        }
      }
    }
    __syncthreads();
    if (tid == 0)
      __hip_atomic_store(&p.ct[vid], (unsigned)(3 * layer + 4),
                         __ATOMIC_RELAXED, __HIP_MEMORY_SCOPE_AGENT);
  }

  // ---------------- mask: y = xe * sigmoid(h) -> yb ----------------
  {
    float* yn = p.yb + (size_t)n * ((size_t)L_ * C_);
#pragma unroll
    for (int jb = 0; jb < 2; ++jb) {
      int gl = l0 + ch * 32 + jb * 16 + frow;
      if (gl < L_) {
        float4 v;
        v.x = xer[jb][0] / (1.f + expf(-hreg[jb][0]));
        v.y = xer[jb][1] / (1.f + expf(-hreg[jb][1]));
        v.z = xer[jb][2] / (1.f + expf(-hreg[jb][2]));
        v.w = xer[jb][3] / (1.f + expf(-hreg[jb][3]));
        *(float4*)(yn + (size_t)gl * C_ + cbase) = v;
      }
    }
  }
  bar_heavy(p.gbar, NVALID, tid);

  // ---------------- decoder ----------------
  for (int idx = vid * NTHR + tid; idx < NBATCH * T_; idx += NVALID * NTHR) {
    int t = idx % T_;
    int nn = idx / T_;
    int tt = t + FK_;
    int lq = tt / 10;      // in [2, 801]
    int k0 = tt % 10;
    const float* y0 = p.yb + (size_t)nn * ((size_t)L_ * C_) + (size_t)lq * C_;
    const float* y1 = y0 - C_;
    float acc = 0.f;
#pragma unroll 8
    for (int c = 0; c < C_; c++) {
      const float* wr2 = p.w_dec + c * FK_;
      acc = fmaf(y0[c], wr2[k0], acc);
      acc = fmaf(y1[c], wr2[k0 + 10], acc);
    }
    p.out[idx] = acc;
  }
}

extern "C" void kernel_launch(void* const* d_in, const int* in_sizes, int n_in,
                              void* d_out, int out_size, void* d_ws, size_t ws_size,
                              hipStream_t stream) {
  KParams hp;
  hp.x     = (const float*)d_in[0];
  hp.w_enc = (const float*)d_in[1];
  hp.w1    = (const float*)d_in[2];
  hp.wd    = (const float*)d_in[3];
  hp.w2    = (const float*)d_in[4];
  hp.w_dec = (const float*)d_in[5];
  hp.g1 = (const float*)d_in[6];  hp.bb1 = (const float*)d_in[7];
  hp.m1 = (const float*)d_in[8];  hp.v1  = (const float*)d_in[9];
  hp.g2 = (const float*)d_in[10]; hp.bb2 = (const float*)d_in[11];
  hp.m2 = (const float*)d_in[12]; hp.v2  = (const float*)d_in[13];
  hp.g3 = (const float*)d_in[14]; hp.bb3 = (const float*)d_in[15];
  hp.m3 = (const float*)d_in[16]; hp.v3  = (const float*)d_in[17];
  hp.out = (float*)d_out;

  char* cur = (char*)d_ws;
  auto take = [&](size_t bytes) { char* r = cur; cur += (bytes + 255) & ~(size_t)255; return r; };
  hp.gbar = (Bar*)take(256);
  hp.ct   = (unsigned*)take(NVALID * 4);
  hp.s1 = (float*)take(NB_ * C_ * 4);
  hp.o1 = (float*)take(NB_ * C_ * 4);
  hp.s2 = (float*)take(NB_ * D_ * 4);
  hp.o2 = (float*)take(NB_ * D_ * 4);
  hp.s3 = (float*)take(NB_ * D_ * 4);
  hp.o3 = (float*)take(NB_ * D_ * 4);
  hp.yb  = (float*)take((size_t)NBATCH * L_ * C_ * 4);
  hp.w1b = (short*)take((size_t)NB_ * D_ * C_ * 2);
  hp.w2b = (short*)take((size_t)NB_ * D_ * C_ * 2);
  hp.b1b = (unsigned short*)take((size_t)NB_ * NBATCH * L_ * C_ * 2);     // 32 bufs
  hp.b3g = (unsigned short*)take((size_t)16 * 52 * 64 * 512 * 2);         // 16 bufs
  hp.zh  = (unsigned short*)take((size_t)NB_ * 52 * 4 * 64 * 128 * 2);    // 32 bufs

  hipMemsetAsync(d_ws, 0, 2048, stream);   // gbar + ct
  prep_kernel<<<dim3(1024), dim3(256), 0, stream>>>(hp);
  tasnet_fused<<<dim3(NGRID), dim3(NTHR), 0, stream>>>(hp);
}